// Round 2
// baseline (20573.976 us; speedup 1.0000x reference)
//
#include <hip/hip_runtime.h>

// Problem constants
#define Bn 32
#define Tn 1024
#define Dn 512
#define Hn 512
#define Vn 64
#define Sn 128
#define NTS 8          // t-slices per batch = group size
#define TT 128         // T per block
#define NU 64          // H-units per block
#define NTHREADS 512
#define KIH 576        // W_ih cols (V + H)

#define LDS_BYTES 139264
#define OUT_ATT ((size_t)Sn * Bn * Vn)

struct F8 { float4 a, b; };

__device__ __forceinline__ float bfu(unsigned short u){ return __uint_as_float(((unsigned int)u)<<16); }
__device__ __forceinline__ float bflo(unsigned int u){ return __uint_as_float(u<<16); }
__device__ __forceinline__ float bfhi(unsigned int u){ return __uint_as_float(u & 0xffff0000u); }
__device__ __forceinline__ unsigned short f2bf(float f){
  unsigned int x = __float_as_uint(f);
  return (unsigned short)((x + 0x7fffu + ((x>>16)&1u)) >> 16);   // RNE
}

// overloaded loads: 8 input elements -> 8 f32
__device__ __forceinline__ F8 ld8(const unsigned short* p){
  uint4 q = *(const uint4*)p;
  F8 r;
  r.a = make_float4(bflo(q.x), bfhi(q.x), bflo(q.y), bfhi(q.y));
  r.b = make_float4(bflo(q.z), bfhi(q.z), bflo(q.w), bfhi(q.w));
  return r;
}
__device__ __forceinline__ F8 ld8(const float* p){
  F8 r; r.a = *(const float4*)p; r.b = *(const float4*)(p+4); return r;
}
__device__ __forceinline__ float ldv(const unsigned short* p){ return bfu(*p); }
__device__ __forceinline__ float ldv(const float* p){ return *p; }
__device__ __forceinline__ void st(unsigned short* p, float v){ *p = f2bf(v); }
__device__ __forceinline__ void st(float* p, float v){ *p = v; }

__device__ __forceinline__ float dot8(F8 w, float4 a, float4 b){
  return w.a.x*a.x + w.a.y*a.y + w.a.z*a.z + w.a.w*a.w
       + w.b.x*b.x + w.b.y*b.y + w.b.z*b.z + w.b.w*b.w;
}
template<typename T>
__device__ __forceinline__ float dot64g(const T* __restrict__ w, const float* x){
  const float4* x4 = (const float4*)x;
  float acc = 0.f;
#pragma unroll
  for(int i=0;i<8;i++) acc += dot8(ld8(w+8*i), x4[2*i], x4[2*i+1]);
  return acc;
}

// clamped activations: no exp-overflow path exists (clamps are exact at f32 precision)
__device__ __forceinline__ float sigm(float x){
  x = fminf(fmaxf(x, -30.f), 30.f); return 1.f/(1.f + expf(-x));
}
__device__ __forceinline__ float tnh(float x){
  return tanhf(fminf(fmaxf(x, -20.f), 20.f));
}

template<bool B> struct Sel { using T = unsigned short; };
template<> struct Sel<false> { using T = float; };

// ---- relaxed agent-scope atomics for cross-XCD ws data ----
__device__ __forceinline__ void aput(float* p, float v){
  __hip_atomic_store(p, v, __ATOMIC_RELAXED, __HIP_MEMORY_SCOPE_AGENT);
}
__device__ __forceinline__ float aget(const float* p){
  return __hip_atomic_load(p, __ATOMIC_RELAXED, __HIP_MEMORY_SCOPE_AGENT);
}
__device__ __forceinline__ unsigned int uget(const unsigned int* p){
  return __hip_atomic_load(p, __ATOMIC_RELAXED, __HIP_MEMORY_SCOPE_AGENT);
}

// 8-block group generation barrier (monotonic counters, relaxed atomics only).
__device__ __forceinline__ void gbar(unsigned int* bar){
  asm volatile("s_waitcnt vmcnt(0)" ::: "memory");  // prior ws stores acked at LLC
  __syncthreads();
  if(threadIdx.x==0){
    unsigned int g = uget(bar+1);
    unsigned int p = __hip_atomic_fetch_add(bar, 1u, __ATOMIC_RELAXED, __HIP_MEMORY_SCOPE_AGENT);
    if(p == g*NTS + (NTS-1)){
      __hip_atomic_store(bar+1, g+1u, __ATOMIC_RELAXED, __HIP_MEMORY_SCOPE_AGENT);
    } else {
      while(uget(bar+1) == g)
        __builtin_amdgcn_s_sleep(2);
    }
  }
  __syncthreads();
  asm volatile("" ::: "memory");
}

// dtype probe: b_ih ~ N(0, 0.01^2). flag: 1 = bf16, 2 = f32.
__global__ void dtype_probe(const unsigned short* __restrict__ b3, unsigned int* flag){
  const int t = threadIdx.x;
  bool ok = true;
#pragma unroll
  for(int i=0;i<8;i++){
    float v = bfu(b3[2*(t*8+i)]);
    ok = ok && (v == v) && (fabsf(v) < 0.5f);
  }
  unsigned long long m = __ballot(ok);
  if(t == 0)
    __hip_atomic_store(flag, (m == ~0ull) ? 1u : 2u, __ATOMIC_RELEASE, __HIP_MEMORY_SCOPE_AGENT);
}

template<bool BF>
__global__ __launch_bounds__(NTHREADS, 2)
void speller_persist(const void* __restrict__ lf_,   const void* __restrict__ wih_,
                     const void* __restrict__ whh_,  const void* __restrict__ bih_,
                     const void* __restrict__ bhh_,  const void* __restrict__ wout_,
                     const void* __restrict__ bout_, void* __restrict__ out_,
                     float* __restrict__ ws)
{
  // self-select on the probed dtype; the wrong instantiation exits immediately
  {
    unsigned int fl = __hip_atomic_load((unsigned int*)ws + 512, __ATOMIC_ACQUIRE, __HIP_MEMORY_SCOPE_AGENT);
    if(fl != (BF ? 1u : 2u)) return;
  }
  using T = typename Sel<BF>::T;
  const T* lf   = (const T*)lf_;
  const T* wih  = (const T*)wih_;
  const T* whh  = (const T*)whh_;
  const T* bih  = (const T*)bih_;
  const T* bhh  = (const T*)bhh_;
  const T* wout = (const T*)wout_;
  const T* bout = (const T*)bout_;
  T* out = (T*)out_;

  const int tid = threadIdx.x;

  extern __shared__ char smem[];
  // tile region [0,131072): BF path = bf16 [128][512]; f32 path = f32 [64][512] XOR-swizzled
  unsigned short* lf_s = (unsigned short*)smem;
  float* epart = (float*)(smem + 131072);                 // [512] energy wave-partials (f32 path)
  float* h_s   = epart + 512;                             // [512] h(s)
  float* ctx_s = h_s + 512;                               // [512] ctx(s-1)
  float* e_s   = ctx_s + 512;                             // [128] raw energies (persist over barrier)
  float* p_s   = e_s + 128;                               // [128] exp(e - m_local)
  float* lg_s  = p_s + 128;                               // [64] logits
  float* red_s = lg_s + 64;                               // [0..7]=fac,[8]=m,[9]=l,[10]=m_loc,[16..23]=mst,[24..31]=lst
  float* c_s   = red_s + 32;                              // [64] LSTM cell state
  int*   i_s   = (int*)(c_s + 64);                        // [0]=prev argmax, [1]=b, [2]=ts

  // --- XCD-aware (b, ts) claiming -------------------------------------------
  // All blocks on the same XCD claim the same ts => the per-XCD weight working
  // set (W_ih slice 589KB + W_hh slice 524KB + W_out 256KB) is unique per XCD
  // and fully L2-resident, instead of 8 slices (8.7MB) thrashing a 4MB L2.
  // Ticket scheme is deadlock-free: all 256 blocks are co-resident (LDS-sized
  // to 1 block/CU), each makes exactly one preferred claim; spill claims wait
  // only on claims by resident blocks, then map deterministically to free slots.
  {
    unsigned int* tick = (unsigned int*)ws + 544;   // [544..552] in zeroed 4KB
    if(tid == 0){
      // HW_REG_XCC_ID = id 20; GETREG imm = id | (offset<<6) | ((size-1)<<11)
      unsigned int xcc = __builtin_amdgcn_s_getreg(20u | (31u << 11)) & 7u;
      unsigned int i = __hip_atomic_fetch_add(tick + xcc, 1u, __ATOMIC_RELAXED, __HIP_MEMORY_SCOPE_AGENT);
      int cls, slot;
      if(i < 32u){ cls = (int)xcc; slot = (int)i; }
      else {
        unsigned int j = __hip_atomic_fetch_add(tick + 8, 1u, __ATOMIC_RELAXED, __HIP_MEMORY_SCOPE_AGENT);
        for(;;){   // wait until all 256 preferred claims are registered
          unsigned int ssum = 0;
#pragma unroll
          for(int c2=0;c2<8;c2++) ssum += uget(tick + c2);
          if(ssum >= 256u) break;
          __builtin_amdgcn_s_sleep(8);
        }
        unsigned int acc = 0; cls = 7; slot = 31;
#pragma unroll
        for(int c2=0;c2<8;c2++){
          unsigned int tc   = uget(tick + c2);
          unsigned int used = tc < 32u ? tc : 32u;
          unsigned int fr   = 32u - used;
          if(j < acc + fr){ cls = c2; slot = (int)(used + (j - acc)); break; }
          acc += fr;
        }
      }
      i_s[1] = slot;   // b
      i_s[2] = cls;    // ts
    }
    __syncthreads();
  }
  const int b  = i_s[1];
  const int ts = i_s[2];

  // ws floats: [0,498)=barriers (u32), [512]=dtype flag (u32), [544..552]=tick (u32),
  // [1024,17408)=hbuf, [17408,17664)=mst, [17664,17920)=lst, [17920,149024)=ctxp
  unsigned int* bar = (unsigned int*)ws + (size_t)b*16;
  float* hbuf = ws + 1024  + (size_t)b*Hn;
  float* mst  = ws + 17408 + (size_t)b*NTS;
  float* lst  = ws + 17664 + (size_t)b*NTS;
  float* ctxp = ws + 17920 + (size_t)b*NTS*Dn;

  // f32 path: rows 64..127 of this block's LF slice live in registers,
  // column-major: thread owns column d = tid, lfreg[j] = LF[ts*128+64+j][tid]
  float lfreg[64];

  // ---------------- init ----------------
  if constexpr (BF){
    const uint4* s4 = (const uint4*)((const unsigned short*)lf_ + ((size_t)b*Tn + (size_t)ts*TT) * Dn);
    uint4* d4 = (uint4*)lf_s;
#pragma unroll
    for(int i=0;i<16;i++) d4[tid + i*NTHREADS] = s4[tid + i*NTHREADS];
  } else {
    // rows 0..63 -> swizzled f32 LDS tile: float4 slot c stored at c ^ (row&7)
    const float4* s4 = (const float4*)((const float*)lf_ + ((size_t)b*Tn + (size_t)ts*TT) * Dn);
    float4* d4 = (float4*)smem;
#pragma unroll
    for(int i=0;i<16;i++){
      const int f = tid + i*NTHREADS;       // float4 index in [0,8192)
      const int row = f >> 7, cc = f & 127; // 128 float4 per row
      d4[(row << 7) | (cc ^ (row & 7))] = s4[f];
    }
    // rows 64..127 -> registers (coalesced column loads)
    const float* lfg = (const float*)lf_ + ((size_t)b*Tn + (size_t)ts*TT + 64) * Dn + tid;
#pragma unroll
    for(int j=0;j<64;j++) lfreg[j] = lfg[(size_t)j*Dn];
  }
  h_s[tid] = 0.f;
  if(tid < NU) c_s[tid] = 0.f;
  if(tid == 0) i_s[0] = 0;
  __syncthreads();

  for(int s = 0; s <= Sn; ++s){
    // ================= P phase =================
    if(s > 0){
      if(tid < NTS){ red_s[16+tid] = aget(&mst[tid]); red_s[24+tid] = aget(&lst[tid]); }
      __syncthreads();
      if(tid == 0){
        float m = -3.0e38f;
#pragma unroll
        for(int j=0;j<NTS;j++) m = fmaxf(m, red_s[16+j]);
        float l = 0.f;
#pragma unroll
        for(int j=0;j<NTS;j++){ float fac = expf(red_s[16+j]-m); red_s[j]=fac; l += fac*red_s[24+j]; }
        red_s[8]=m; red_s[9]=l;
      }
      __syncthreads();
      const float gm = red_s[8];
      const float gl = red_s[9];
      {  // combine + normalize ctx(s-1) (identical in all 8 group blocks)
        float acc = 0.f;
#pragma unroll
        for(int j=0;j<NTS;j++) acc += red_s[j] * aget(&ctxp[(size_t)j*Dn + tid]);
        ctx_s[tid] = acc / gl;
      }
      if(tid < TT){  // attn(s-1) for this slice
        float a = expf(e_s[tid] - gm) / gl;
        st(out + OUT_ATT + ((size_t)(s-1)*Bn + b)*Tn + (size_t)ts*TT + tid, a);
      }
      __syncthreads();
      {  // logits(s-1) = W_out @ [h; ctx] + b_out   (W_out L2-resident per XCD)
        const int j = tid >> 3, ks = tid & 7;
        const T* wr = wout + (size_t)j*(2*Hn) + ks*128;
        float acc;
        if(ks < 4) acc = dot64g(wr, h_s + ks*128)       + dot64g(wr+64, h_s + ks*128 + 64);
        else       acc = dot64g(wr, ctx_s + (ks-4)*128) + dot64g(wr+64, ctx_s + (ks-4)*128 + 64);
#pragma unroll
        for(int off=1; off<8; off<<=1) acc += __shfl_xor(acc, off);
        if(ks==0) lg_s[j] = acc + ldv(bout + j);
      }
      __syncthreads();
      if(tid < Vn){  // wave 0: log_softmax + first-index argmax
        const float lv = lg_s[tid];
        float mv = lv; int mi = tid;
#pragma unroll
        for(int off=1; off<64; off<<=1){
          float ov = __shfl_xor(mv, off);
          int   oi = __shfl_xor(mi, off);
          if(ov > mv || (ov == mv && oi < mi)){ mv = ov; mi = oi; }
        }
        float se = expf(lv - mv);
#pragma unroll
        for(int off=1; off<64; off<<=1) se += __shfl_xor(se, off);
        const float logp = lv - mv - logf(se);
        if(ts == 0) st(out + ((size_t)(s-1)*Bn + b)*Vn + tid, logp);
        if(tid == 0) i_s[0] = mi;
      }
      __syncthreads();
    } else {
      // s==0: x0 = [onehot(0), LF[:,0,:]]
      ctx_s[tid] = ldv(lf + (size_t)b*Tn*Dn + tid);
      __syncthreads();
    }

    if(s == Sn) break;

    // gates: units uu = ts*64+u ; rows i,f,g,o ; K=1024 split 8 ways across ks
    {
      const int u  = tid >> 3;
      const int ks = tid & 7;
      const int uu = ts*NU + u;
      const T* wi0 = wih + (size_t)(       uu)*KIH + 64 + ks*64;
      const T* wi1 = wih + (size_t)(  Hn + uu)*KIH + 64 + ks*64;
      const T* wi2 = wih + (size_t)(2*Hn + uu)*KIH + 64 + ks*64;
      const T* wi3 = wih + (size_t)(3*Hn + uu)*KIH + 64 + ks*64;
      const T* wh0 = whh + (size_t)(       uu)*Hn + ks*64;
      const T* wh1 = whh + (size_t)(  Hn + uu)*Hn + ks*64;
      const T* wh2 = whh + (size_t)(2*Hn + uu)*Hn + ks*64;
      const T* wh3 = whh + (size_t)(3*Hn + uu)*Hn + ks*64;
      const float4* xc = (const float4*)(ctx_s + ks*64);
      const float4* xh = (const float4*)(h_s   + ks*64);
      float a0=0.f,a1=0.f,a2=0.f,a3=0.f;
#pragma unroll
      for(int i=0;i<8;i++){
        float4 p0 = xc[2*i], p1 = xc[2*i+1];
        a0 += dot8(ld8(wi0+8*i), p0, p1);
        a1 += dot8(ld8(wi1+8*i), p0, p1);
        a2 += dot8(ld8(wi2+8*i), p0, p1);
        a3 += dot8(ld8(wi3+8*i), p0, p1);
      }
#pragma unroll
      for(int i=0;i<8;i++){
        float4 p0 = xh[2*i], p1 = xh[2*i+1];
        a0 += dot8(ld8(wh0+8*i), p0, p1);
        a1 += dot8(ld8(wh1+8*i), p0, p1);
        a2 += dot8(ld8(wh2+8*i), p0, p1);
        a3 += dot8(ld8(wh3+8*i), p0, p1);
      }
#pragma unroll
      for(int off=1; off<8; off<<=1){
        a0 += __shfl_xor(a0, off);
        a1 += __shfl_xor(a1, off);
        a2 += __shfl_xor(a2, off);
        a3 += __shfl_xor(a3, off);
      }
      if(ks == 0){
        const int pidx = i_s[0];
        const int r0 = uu, r1 = Hn+uu, r2 = 2*Hn+uu, r3 = 3*Hn+uu;
        float gi = a0 + ldv(wih + (size_t)r0*KIH + pidx) + ldv(bih+r0) + ldv(bhh+r0);
        float gf = a1 + ldv(wih + (size_t)r1*KIH + pidx) + ldv(bih+r1) + ldv(bhh+r1);
        float gg = a2 + ldv(wih + (size_t)r2*KIH + pidx) + ldv(bih+r2) + ldv(bhh+r2);
        float go = a3 + ldv(wih + (size_t)r3*KIH + pidx) + ldv(bih+r3) + ldv(bhh+r3);
        gi = sigm(gi);
        gf = sigm(gf);
        gg = tnh(gg);
        go = sigm(go);
        float c = gf*c_s[u] + gi*gg;
        c_s[u] = c;
        aput(&hbuf[uu], go * tnh(c));
      }
    }
    gbar(bar);

    // ================= Q phase =================
    h_s[tid] = aget(&hbuf[tid]);
    __syncthreads();
    if constexpr (BF){
      {  // energies for 2 local t's per thread (t2 = tid>>3, q = K-octant)
        const int t2 = tid >> 3;
        const int q  = tid & 7;
        const float4* hq = (const float4*)(h_s + q*64);
        float ea=0.f, eb=0.f;
        const unsigned short* la = lf_s + (size_t)(2*t2  )*Dn + q*64;
        const unsigned short* lb = lf_s + (size_t)(2*t2+1)*Dn + q*64;
#pragma unroll
        for(int i=0;i<8;i++){
          float4 p0 = hq[2*i], p1 = hq[2*i+1];
          ea += dot8(ld8(la+8*i), p0, p1);
          eb += dot8(ld8(lb+8*i), p0, p1);
        }
#pragma unroll
        for(int off=1; off<8; off<<=1){ ea += __shfl_xor(ea,off); eb += __shfl_xor(eb,off); }
        if(q==0){ e_s[2*t2] = ea; e_s[2*t2+1] = eb; }
      }
      __syncthreads();
      if(tid < 64){   // slice max
        float v = fmaxf(e_s[tid], e_s[tid+64]);
#pragma unroll
        for(int off=1; off<64; off<<=1) v = fmaxf(v, __shfl_xor(v,off));
        if(tid==0) red_s[10] = v;
      }
    } else {
      {  // rows 0..63: one row per thread from swizzled f32 LDS tile
        const int t1 = tid >> 3, q = tid & 7, mm = t1 & 7;
        const float4* lrow = (const float4*)smem + (size_t)t1*128;
        const float4* hq = (const float4*)(h_s + q*64);
        float ea = 0.f;
#pragma unroll
        for(int i=0;i<8;i++){
          const int c0 = q*16 + 2*i;
          F8 wv; wv.a = lrow[c0 ^ mm]; wv.b = lrow[(c0+1) ^ mm];
          ea += dot8(wv, hq[2*i], hq[2*i+1]);
        }
#pragma unroll
        for(int off=1; off<8; off<<=1) ea += __shfl_xor(ea, off);
        if(q==0) e_s[t1] = ea;
      }
      {  // rows 64..127 from registers: butterfly reduce across the wave per t
        const int lane = tid & 63;
        const float h_own = h_s[tid];
        float mine = 0.f;
#pragma unroll
        for(int j=0;j<64;j++){
          float v = h_own * lfreg[j];
#pragma unroll
          for(int off=1; off<64; off<<=1) v += __shfl_xor(v, off);
          if(lane == j) mine = v;
        }
        epart[tid] = mine;   // [wave][lane] = partial for t=64+lane over wave's d-range
      }
      __syncthreads();
      if(tid < 64){   // cross-wave combine + slice max
        float s2 = 0.f;
#pragma unroll
        for(int w2=0; w2<8; w2++) s2 += epart[(w2<<6) + tid];
        e_s[64 + tid] = s2;
        float v = fmaxf(e_s[tid], s2);
#pragma unroll
        for(int off=1; off<64; off<<=1) v = fmaxf(v, __shfl_xor(v,off));
        if(tid==0) red_s[10] = v;
      }
    }
    __syncthreads();
    if(tid < TT) p_s[tid] = expf(e_s[tid] - red_s[10]);
    __syncthreads();
    if(tid < 64){   // slice sumexp -> publish (m_s, l_s)
      float v = p_s[tid] + p_s[tid+64];
#pragma unroll
      for(int off=1; off<64; off<<=1) v += __shfl_xor(v,off);
      if(tid==0){ aput(&mst[ts], red_s[10]); aput(&lst[ts], v); }
    }
    {  // ctx partial: thread owns one d, sweep 128 t's (LDS half + register half)
      float acc = 0.f;
      if constexpr (BF){
        const unsigned short* col = lf_s + tid;
#pragma unroll 4
        for(int t=0;t<TT;t++) acc += p_s[t] * bfu(col[(size_t)t*Dn]);
      } else {
        const float* base = (const float*)smem;
        const int cs = tid >> 2, cr = tid & 3;
#pragma unroll
        for(int t=0;t<64;t++)
          acc += p_s[t] * base[(size_t)t*Dn + (((cs ^ (t&7))<<2) | cr)];
#pragma unroll
        for(int j=0;j<64;j++) acc += p_s[64+j] * lfreg[j];
      }
      aput(&ctxp[(size_t)ts*Dn + tid], acc);
    }
    gbar(bar);
  }
}

extern "C" void kernel_launch(void* const* d_in, const int* in_sizes, int n_in,
                              void* d_out, int out_size, void* d_ws, size_t ws_size,
                              hipStream_t stream) {
  (void)in_sizes; (void)n_in; (void)out_size; (void)ws_size;
  float* ws = (float*)d_ws;

  hipFuncSetAttribute(reinterpret_cast<const void*>(&speller_persist<true>),
                      hipFuncAttributeMaxDynamicSharedMemorySize, LDS_BYTES);
  hipFuncSetAttribute(reinterpret_cast<const void*>(&speller_persist<false>),
                      hipFuncAttributeMaxDynamicSharedMemorySize, LDS_BYTES);
  // barriers + flag + tickets live in the first 4 KB (d_ws is poisoned 0xAA before every launch)
  hipMemsetAsync(d_ws, 0, 4096, stream);
  // probe b_ih (d_in[3]) to decide bf16 vs f32; writes flag at u32 index 512
  dtype_probe<<<dim3(1), dim3(64), 0, stream>>>((const unsigned short*)d_in[3],
                                                (unsigned int*)d_ws + 512);
  speller_persist<true><<<dim3(Bn*NTS), dim3(NTHREADS), LDS_BYTES, stream>>>(
      d_in[0], d_in[1], d_in[2], d_in[3], d_in[4], d_in[5], d_in[6], d_out, ws);
  speller_persist<false><<<dim3(Bn*NTS), dim3(NTHREADS), LDS_BYTES, stream>>>(
      d_in[0], d_in[1], d_in[2], d_in[3], d_in[4], d_in[5], d_in[6], d_out, ws);
}

// Round 4
// 9101.686 us; speedup vs baseline: 2.2605x; 2.2605x over previous
//
#include <hip/hip_runtime.h>

// Problem constants
#define Bn 32
#define Tn 1024
#define Dn 512
#define Hn 512
#define Vn 64
#define Sn 128
#define NTS 8          // t-slices per batch
#define TT 128         // T per block (attention role)
#define NTHREADS 512
#define KIH 576        // W_ih cols (V + H)
#define NBLK 256

// LDS: 131072 (tile) + 9248 (scratch incl. wow_s) = 140320 -> 143360 (1 blk/CU)
#define LDS_BYTES 143360
#define OUT_ATT ((size_t)Sn * Bn * Vn)

// ws float-index layout (v3 kernel)
#define WS_BAR   0        // u32[16]: [0]=global arrival counter (monotonic)
#define WS_FLAG  512      // u32 dtype flag (written by probe)
#define WS_XCTX  1024     // [32][512]  ctx(s-1)
#define WS_XH    17408    // [2][32][512] h double-buffered by step parity
#define WS_LGP   50176    // [32][64][8] logits partials
#define WS_MST   66560    // [32][8]
#define WS_LST   66816    // [32][8]
#define WS_CTXP  67072    // [32][8][512]
// total = 198144 floats = 792.6 KB

struct F8 { float4 a, b; };

__device__ __forceinline__ float bfu(unsigned short u){ return __uint_as_float(((unsigned int)u)<<16); }
__device__ __forceinline__ float bflo(unsigned int u){ return __uint_as_float(u<<16); }
__device__ __forceinline__ float bfhi(unsigned int u){ return __uint_as_float(u & 0xffff0000u); }
__device__ __forceinline__ unsigned short f2bf(float f){
  unsigned int x = __float_as_uint(f);
  return (unsigned short)((x + 0x7fffu + ((x>>16)&1u)) >> 16);   // RNE
}
__device__ __forceinline__ F8 ld8(const unsigned short* p){
  uint4 q = *(const uint4*)p;
  F8 r;
  r.a = make_float4(bflo(q.x), bfhi(q.x), bflo(q.y), bfhi(q.y));
  r.b = make_float4(bflo(q.z), bfhi(q.z), bflo(q.w), bfhi(q.w));
  return r;
}
__device__ __forceinline__ F8 ld8(const float* p){
  F8 r; r.a = *(const float4*)p; r.b = *(const float4*)(p+4); return r;
}
__device__ __forceinline__ float dot8(F8 w, float4 a, float4 b){
  return w.a.x*a.x + w.a.y*a.y + w.a.z*a.z + w.a.w*a.w
       + w.b.x*b.x + w.b.y*b.y + w.b.z*b.z + w.b.w*b.w;
}
__device__ __forceinline__ float dot64g(const unsigned short* __restrict__ w, const float* x){
  const float4* x4 = (const float4*)x;
  float acc = 0.f;
#pragma unroll
  for(int i=0;i<8;i++) acc += dot8(ld8(w+8*i), x4[2*i], x4[2*i+1]);
  return acc;
}
__device__ __forceinline__ float sigm(float x){
  x = fminf(fmaxf(x, -30.f), 30.f); return 1.f/(1.f + expf(-x));
}
__device__ __forceinline__ float tnh(float x){
  return tanhf(fminf(fmaxf(x, -20.f), 20.f));
}

// ---- relaxed agent-scope atomics (write-through to the coherence point) ----
__device__ __forceinline__ void aput(float* p, float v){
  __hip_atomic_store(p, v, __ATOMIC_RELAXED, __HIP_MEMORY_SCOPE_AGENT);
}
__device__ __forceinline__ float aget(const float* p){
  return __hip_atomic_load(p, __ATOMIC_RELAXED, __HIP_MEMORY_SCOPE_AGENT);
}
__device__ __forceinline__ unsigned int uget(const unsigned int* p){
  return __hip_atomic_load(p, __ATOMIC_RELAXED, __HIP_MEMORY_SCOPE_AGENT);
}

// Global 256-block barrier: monotonic arrival counter. Release on arrival
// (drains write-through stores), relaxed polls, ONE acquire load on exit so
// that subsequent PLAIN vectorized loads are coherent (agent-acquire
// invalidates L1+L2; cheap here because nothing valuable is cached).
__device__ __forceinline__ void gbar_all(unsigned int* bar, unsigned int gen){
  asm volatile("s_waitcnt vmcnt(0)" ::: "memory");
  __syncthreads();
  if(threadIdx.x == 0){
    __hip_atomic_fetch_add(bar, 1u, __ATOMIC_RELEASE, __HIP_MEMORY_SCOPE_AGENT);
    const unsigned int tgt = gen * (unsigned int)NBLK;
    while(uget(bar) < tgt) __builtin_amdgcn_s_sleep(4);
    while(__hip_atomic_load(bar, __ATOMIC_ACQUIRE, __HIP_MEMORY_SCOPE_AGENT) < tgt)
      __builtin_amdgcn_s_sleep(1);
  }
  __syncthreads();
  asm volatile("" ::: "memory");
}

// dtype probe: b_ih ~ N(0,0.01^2). flag: 1 = bf16, 2 = f32.
__global__ void dtype_probe(const unsigned short* __restrict__ b3, unsigned int* flag){
  const int t = threadIdx.x;
  bool ok = true;
#pragma unroll
  for(int i=0;i<8;i++){
    float v = bfu(b3[2*(t*8+i)]);
    ok = ok && (v == v) && (fabsf(v) < 0.5f);
  }
  unsigned long long m = __ballot(ok);
  if(t == 0)
    __hip_atomic_store(flag, (m == ~0ull) ? 1u : 2u, __ATOMIC_RELEASE, __HIP_MEMORY_SCOPE_AGENT);
}

// ============================================================================
// v3 (f32 inputs): weights persist on-chip.
//  - Gates role: block UP owns units {2UP, 2UP+1} x 4 gates = 8 rows <-> 8 waves.
//    Lane holds 16-float row chunk in registers (lanes 0..31: W_ih ctx cols,
//    lanes 32..63: W_hh). One-hot W_ih cols + biases in LDS.
//  - Attention role: (b,ts) = (UP>>3, UP&7); LF rows 0..63 in swizzled LDS,
//    rows 64..127 column-major in registers (as round-1).
//  - W_out K-sliced: 16 floats/thread in registers.
//  - Per step: G (logits/argmax + gates) -> bar -> E (attention) -> bar ->
//    C (ctx combine + attn out + logits partials) -> bar.
// ============================================================================
__global__ __launch_bounds__(NTHREADS, 2)
void speller_v3(const float* __restrict__ lf,  const float* __restrict__ wih,
                const float* __restrict__ whh, const float* __restrict__ bih,
                const float* __restrict__ bhh, const float* __restrict__ wout,
                const float* __restrict__ bout, float* __restrict__ out,
                float* __restrict__ ws)
{
  { unsigned int fl = __hip_atomic_load((unsigned int*)ws + WS_FLAG, __ATOMIC_ACQUIRE, __HIP_MEMORY_SCOPE_AGENT);
    if(fl != 2u) return; }

  const int tid   = threadIdx.x;
  const int UP    = (int)blockIdx.x;      // unit-pair id; units 2UP, 2UP+1
  const int b_att = UP >> 3;              // attention batch
  const int ts    = UP & 7;               // attention t-slice
  const int w     = tid >> 6;             // wave 0..7
  const int lane  = tid & 63;

  extern __shared__ char smem[];
  float* tile   = (float*)smem;                 // [64][512] f32 swizzled LF rows 0..63
  float* epart  = (float*)(smem + 131072);      // [512]
  float* h_s    = epart + 512;                  // [512]
  float* e_s    = h_s + 512;                    // [128]
  float* p_s    = e_s + 128;                    // [128]
  float* red_s  = p_s + 128;                    // [32]
  float* pre_s  = red_s + 32;                   // [8][32] gate pre-activations
  float* ctxc_s = pre_s + 256;                  // [64] combined ctx chunk
  float* c_s    = ctxc_s + 64;                  // [64] cell state (bb*2+ul)
  float* bias_s = c_s + 64;                     // [8]
  float* bout_s = bias_s + 8;                   // [64]
  int*   pall_s = (int*)(bout_s + 64);          // [32] argmax per batch
  float* wow_s  = (float*)(pall_s + 32);        // [8][64] W_ih one-hot cols
  // end of scratch = 131072 + 9248 = 140320 <= LDS_BYTES

  unsigned int* bar = (unsigned int*)ws + WS_BAR;
  float* xctx = ws + WS_XCTX;
  float* xh   = ws + WS_XH;
  float* lgp  = ws + WS_LGP;
  float* mst  = ws + WS_MST;
  float* lst  = ws + WS_LST;
  float* ctxp = ws + WS_CTXP;

  // this wave's gate-row: g = w>>1, unit = 2UP + (w&1)
  const int rw = (w>>1)*Hn + 2*UP + (w&1);

  // ---- persistent weight registers ----
  float4 wv0, wv1, wv2, wv3;      // 16-float gate-row chunk
  {
    const int k0 = 16*lane;
    const float* wp = (lane < 32) ? (wih + (size_t)rw*KIH + 64 + k0)
                                  : (whh + (size_t)rw*Hn + (k0 - 512));
    wv0 = *(const float4*)wp;     wv1 = *(const float4*)(wp+4);
    wv2 = *(const float4*)(wp+8); wv3 = *(const float4*)(wp+12);
  }
  float4 oh0, oh1, oc0, oc1;      // W_out K-slice: h-cols and ctx-cols
  {
    const int v = tid>>3, q = tid&7;
    const float* pH = wout + (size_t)v*(2*Hn) + ts*64 + q*8;
    const float* pC = pH + Hn;
    oh0 = *(const float4*)pH; oh1 = *(const float4*)(pH+4);
    oc0 = *(const float4*)pC; oc1 = *(const float4*)(pC+4);
  }

  // ---- LDS weight/aux fills ----
  {
    const int rr = tid>>6, cc = tid&63;
    const int r2 = (rr>>1)*Hn + 2*UP + (rr&1);
    wow_s[tid] = wih[(size_t)r2*KIH + cc];
  }
  if(tid < 8){ const int r2 = (tid>>1)*Hn + 2*UP + (tid&1); bias_s[tid] = bih[r2] + bhh[r2]; }
  if(tid < Vn) bout_s[tid] = bout[tid];
  if(tid < 64) c_s[tid] = 0.f;
  if(tid < 32) pall_s[tid] = 0;

  // ---- LF staging: rows 0..63 -> swizzled LDS; rows 64..127 -> registers ----
  float lfreg[64];
  {
    const float4* s4 = (const float4*)(lf + ((size_t)b_att*Tn + (size_t)ts*TT) * Dn);
    float4* d4 = (float4*)tile;
#pragma unroll
    for(int i=0;i<16;i++){
      const int f = tid + i*NTHREADS;       // float4 index in [0,8192)
      const int row = f >> 7, cc = f & 127;
      d4[(row << 7) | (cc ^ (row & 7))] = s4[f];
    }
    const float* lfg = lf + ((size_t)b_att*Tn + (size_t)ts*TT + 64) * Dn + tid;
#pragma unroll
    for(int j=0;j<64;j++) lfreg[j] = lfg[(size_t)j*Dn];
  }

  // ---- ws init: ctx(-1) = LF[:,0,:]; h(-1) = 0 (parity buffer 1) ----
  if(tid < 64){
    aput(&xctx[(size_t)b_att*Dn + ts*64 + tid], lf[(size_t)b_att*Tn*Dn + ts*64 + tid]);
    const int bb = tid>>1, ul = tid&1;
    aput(&xh[(size_t)Bn*Hn + (size_t)bb*Hn + 2*UP + ul], 0.f);
  }
  __syncthreads();
  unsigned int gen = 0;
  gbar_all(bar, ++gen);

  for(int s = 0; s <= Sn; ++s){
    // ================= G phase =================
    if(s > 0){   // logits(s-1) assembly + argmax (all blocks) + logp (writer blocks)
      for(int ii=0; ii<4; ++ii){
        const int bb = 4*w + ii;
        float lv = bout_s[lane];
        const float4* lp = (const float4*)(lgp + ((size_t)bb*Vn + lane)*8);
        float4 qa = lp[0], qb = lp[1];
        lv += qa.x+qa.y+qa.z+qa.w + qb.x+qb.y+qb.z+qb.w;
        float mv = lv; int mi = lane;
#pragma unroll
        for(int off=1; off<64; off<<=1){
          float ov = __shfl_xor(mv, off);
          int   oi = __shfl_xor(mi, off);
          if(ov > mv || (ov == mv && oi < mi)){ mv = ov; mi = oi; }
        }
        float se = expf(lv - mv);
#pragma unroll
        for(int off=1; off<64; off<<=1) se += __shfl_xor(se, off);
        if(lane == 0) pall_s[bb] = mi;
        if(UP == 8*bb) out[((size_t)(s-1)*Bn + bb)*Vn + lane] = lv - mv - logf(se);
      }
    }
    if(s == Sn) break;
    __syncthreads();   // pall_s ready

    // gates GEMM: wave = row, lane = 16-dim K chunk, loop over 32 batches
    {
      const float* xhR = xh + (size_t)(((s+1)&1))*Bn*Hn;   // h(s-1)
      const int k0 = 16*lane;
      for(int bb=0; bb<Bn; ++bb){
        const float* xp = (lane < 32) ? (xctx + (size_t)bb*Dn + k0)
                                      : (xhR  + (size_t)bb*Hn + (k0 - 512));
        float4 x0 = *(const float4*)xp,     x1 = *(const float4*)(xp+4),
               x2 = *(const float4*)(xp+8), x3 = *(const float4*)(xp+12);
        float acc = wv0.x*x0.x + wv0.y*x0.y + wv0.z*x0.z + wv0.w*x0.w
                  + wv1.x*x1.x + wv1.y*x1.y + wv1.z*x1.z + wv1.w*x1.w
                  + wv2.x*x2.x + wv2.y*x2.y + wv2.z*x2.z + wv2.w*x2.w
                  + wv3.x*x3.x + wv3.y*x3.y + wv3.z*x3.z + wv3.w*x3.w;
#pragma unroll
        for(int off=1; off<64; off<<=1) acc += __shfl_xor(acc, off);
        if(lane == 0) pre_s[w*Bn + bb] = acc;
      }
    }
    __syncthreads();
    if(tid < 64){   // c,h update: 2 units x 32 batches
      const int bb = tid>>1, ul = tid&1;
      const int pidx = pall_s[bb];
      float gi = sigm(pre_s[(0+ul)*Bn+bb] + wow_s[(0+ul)*64+pidx] + bias_s[0+ul]);
      float gf = sigm(pre_s[(2+ul)*Bn+bb] + wow_s[(2+ul)*64+pidx] + bias_s[2+ul]);
      float gg = tnh (pre_s[(4+ul)*Bn+bb] + wow_s[(4+ul)*64+pidx] + bias_s[4+ul]);
      float go = sigm(pre_s[(6+ul)*Bn+bb] + wow_s[(6+ul)*64+pidx] + bias_s[6+ul]);
      float c = gf*c_s[tid] + gi*gg;
      c_s[tid] = c;
      aput(&xh[(size_t)(s&1)*Bn*Hn + (size_t)bb*Hn + 2*UP + ul], go*tnh(c));
    }
    gbar_all(bar, ++gen);

    // ================= E phase (attention) =================
    h_s[tid] = xh[(size_t)(s&1)*Bn*Hn + (size_t)b_att*Hn + tid];
    __syncthreads();
    {  // rows 0..63: one row per thread-group from swizzled tile
      const int t1 = tid >> 3, q = tid & 7, mm = t1 & 7;
      const float4* lrow = (const float4*)tile + (size_t)t1*128;
      const float4* hq = (const float4*)(h_s + q*64);
      float ea = 0.f;
#pragma unroll
      for(int i=0;i<8;i++){
        const int c0 = q*16 + 2*i;
        F8 wv; wv.a = lrow[c0 ^ mm]; wv.b = lrow[(c0+1) ^ mm];
        ea += dot8(wv, hq[2*i], hq[2*i+1]);
      }
#pragma unroll
      for(int off=1; off<8; off<<=1) ea += __shfl_xor(ea, off);
      if(q==0) e_s[t1] = ea;
    }
    {  // rows 64..127: butterfly over register columns
      const float h_own = h_s[tid];
      float mine = 0.f;
#pragma unroll
      for(int j=0;j<64;j++){
        float v = h_own * lfreg[j];
#pragma unroll
        for(int off=1; off<64; off<<=1) v += __shfl_xor(v, off);
        if(lane == j) mine = v;
      }
      epart[tid] = mine;
    }
    __syncthreads();
    if(tid < 64){
      float s2 = 0.f;
#pragma unroll
      for(int w2=0; w2<8; w2++) s2 += epart[(w2<<6) + tid];
      e_s[64 + tid] = s2;
      float v = fmaxf(e_s[tid], s2);
#pragma unroll
      for(int off=1; off<64; off<<=1) v = fmaxf(v, __shfl_xor(v,off));
      if(tid==0) red_s[10] = v;
    }
    __syncthreads();
    if(tid < TT) p_s[tid] = expf(e_s[tid] - red_s[10]);
    __syncthreads();
    if(tid < 64){
      float v = p_s[tid] + p_s[tid+64];
#pragma unroll
      for(int off=1; off<64; off<<=1) v += __shfl_xor(v,off);
      if(tid==0){
        aput(&mst[(size_t)b_att*NTS + ts], red_s[10]);
        aput(&lst[(size_t)b_att*NTS + ts], v);
      }
    }
    {  // ctx partial: thread owns one d, sweep 128 t's
      float acc = 0.f;
      const int cs = tid >> 2, cr = tid & 3;
#pragma unroll
      for(int t=0;t<64;t++)
        acc += p_s[t] * tile[(size_t)t*Dn + (((cs ^ (t&7))<<2) | cr)];
#pragma unroll
      for(int j=0;j<64;j++) acc += p_s[64+j] * lfreg[j];
      aput(&ctxp[((size_t)b_att*NTS + ts)*Dn + tid], acc);
    }
    gbar_all(bar, ++gen);

    // ================= C phase =================
    if(tid < NTS){
      red_s[16+tid] = mst[(size_t)b_att*NTS + tid];
      red_s[24+tid] = lst[(size_t)b_att*NTS + tid];
    }
    __syncthreads();
    if(tid == 0){
      float m = -3.0e38f;
#pragma unroll
      for(int j=0;j<NTS;j++) m = fmaxf(m, red_s[16+j]);
      float l = 0.f;
#pragma unroll
      for(int j=0;j<NTS;j++){ float fac = expf(red_s[16+j]-m); red_s[j]=fac; l += fac*red_s[24+j]; }
      red_s[8]=m; red_s[9]=l;
    }
    __syncthreads();
    {
      const float gm = red_s[8];
      const float gl = red_s[9];
      if(tid < TT)
        out[OUT_ATT + ((size_t)s*Bn + b_att)*Tn + (size_t)ts*TT + tid] = expf(e_s[tid] - gm)/gl;
      if(tid < 64){
        const int d = ts*64 + tid;
        float acc = 0.f;
#pragma unroll
        for(int j=0;j<NTS;j++) acc += red_s[j] * ctxp[((size_t)b_att*NTS + j)*Dn + d];
        const float cv = acc / gl;
        ctxc_s[tid] = cv;
        aput(&xctx[(size_t)b_att*Dn + d], cv);
      }
    }
    __syncthreads();
    {  // logits partial over this block's K chunk
      const int v = tid>>3, q = tid&7;
      const float4* hp = (const float4*)(h_s + ts*64 + q*8);
      const float4* cp = (const float4*)(ctxc_s + q*8);
      float4 ha = hp[0], hb = hp[1], ca = cp[0], cb = cp[1];
      float acc = oh0.x*ha.x + oh0.y*ha.y + oh0.z*ha.z + oh0.w*ha.w
                + oh1.x*hb.x + oh1.y*hb.y + oh1.z*hb.z + oh1.w*hb.w
                + oc0.x*ca.x + oc0.y*ca.y + oc0.z*ca.z + oc0.w*ca.w
                + oc1.x*cb.x + oc1.y*cb.y + oc1.z*cb.z + oc1.w*cb.w;
#pragma unroll
      for(int off=1; off<8; off<<=1) acc += __shfl_xor(acc, off);
      if(q == 0) aput(&lgp[((size_t)b_att*Vn + v)*8 + ts], acc);
    }
    gbar_all(bar, ++gen);
  }
}

// ============================================================================
// bf16-input fallback: round-1 structure (passed), per-batch barrier groups.
// ============================================================================
__device__ __forceinline__ void gbar8(unsigned int* bar){
  asm volatile("s_waitcnt vmcnt(0)" ::: "memory");
  __syncthreads();
  if(threadIdx.x==0){
    unsigned int g = uget(bar+1);
    unsigned int p = __hip_atomic_fetch_add(bar, 1u, __ATOMIC_RELAXED, __HIP_MEMORY_SCOPE_AGENT);
    if(p == g*NTS + (NTS-1)){
      __hip_atomic_store(bar+1, g+1u, __ATOMIC_RELAXED, __HIP_MEMORY_SCOPE_AGENT);
    } else {
      while(uget(bar+1) == g) __builtin_amdgcn_s_sleep(2);
    }
  }
  __syncthreads();
  asm volatile("" ::: "memory");
}

__global__ __launch_bounds__(NTHREADS, 2)
void speller_bf16(const unsigned short* __restrict__ lf, const unsigned short* __restrict__ wih,
                  const unsigned short* __restrict__ whh, const unsigned short* __restrict__ bih,
                  const unsigned short* __restrict__ bhh, const unsigned short* __restrict__ wout,
                  const unsigned short* __restrict__ bout, unsigned short* __restrict__ out,
                  float* __restrict__ ws)
{
  { unsigned int fl = __hip_atomic_load((unsigned int*)ws + WS_FLAG, __ATOMIC_ACQUIRE, __HIP_MEMORY_SCOPE_AGENT);
    if(fl != 1u) return; }
  const int tid = threadIdx.x;
  const int b   = (int)(blockIdx.x >> 3);
  const int ts  = (int)(blockIdx.x & 7);

  extern __shared__ char smem[];
  unsigned short* lf_s = (unsigned short*)smem;           // [128][512] bf16
  float* h_s   = (float*)(smem + 131072);
  float* ctx_s = h_s + 512;
  float* e_s   = ctx_s + 512;
  float* p_s   = e_s + 128;
  float* lg_s  = p_s + 128;
  float* red_s = lg_s + 64;
  float* c_s   = red_s + 32;
  int*   i_s   = (int*)(c_s + 64);

  unsigned int* bar = (unsigned int*)ws + (size_t)b*16;
  float* hbuf = ws + 1024  + (size_t)b*Hn;
  float* mstB = ws + 17408 + (size_t)b*NTS;
  float* lstB = ws + 17664 + (size_t)b*NTS;
  float* ctxpB= ws + 17920 + (size_t)b*NTS*Dn;

  {
    const uint4* s4 = (const uint4*)(lf + ((size_t)b*Tn + (size_t)ts*TT) * Dn);
    uint4* d4 = (uint4*)lf_s;
#pragma unroll
    for(int i=0;i<16;i++) d4[tid + i*NTHREADS] = s4[tid + i*NTHREADS];
  }
  h_s[tid] = 0.f;
  if(tid < 64) c_s[tid] = 0.f;
  if(tid == 0) i_s[0] = 0;
  __syncthreads();

  for(int s = 0; s <= Sn; ++s){
    if(s > 0){
      if(tid < NTS){ red_s[16+tid] = aget(&mstB[tid]); red_s[24+tid] = aget(&lstB[tid]); }
      __syncthreads();
      if(tid == 0){
        float m = -3.0e38f;
#pragma unroll
        for(int j=0;j<NTS;j++) m = fmaxf(m, red_s[16+j]);
        float l = 0.f;
#pragma unroll
        for(int j=0;j<NTS;j++){ float fac = expf(red_s[16+j]-m); red_s[j]=fac; l += fac*red_s[24+j]; }
        red_s[8]=m; red_s[9]=l;
      }
      __syncthreads();
      const float gm = red_s[8];
      const float gl = red_s[9];
      {
        float acc = 0.f;
#pragma unroll
        for(int j=0;j<NTS;j++) acc += red_s[j] * aget(&ctxpB[(size_t)j*Dn + tid]);
        ctx_s[tid] = acc / gl;
      }
      if(tid < TT)
        out[OUT_ATT + ((size_t)(s-1)*Bn + b)*Tn + (size_t)ts*TT + tid] = f2bf(expf(e_s[tid]-gm)/gl);
      __syncthreads();
      {
        const int j = tid >> 3, ks = tid & 7;
        const unsigned short* wr = wout + (size_t)j*(2*Hn) + ks*128;
        float acc;
        if(ks < 4) acc = dot64g(wr, h_s + ks*128)       + dot64g(wr+64, h_s + ks*128 + 64);
        else       acc = dot64g(wr, ctx_s + (ks-4)*128) + dot64g(wr+64, ctx_s + (ks-4)*128 + 64);
#pragma unroll
        for(int off=1; off<8; off<<=1) acc += __shfl_xor(acc, off);
        if(ks==0) lg_s[j] = acc + bfu(bout[j]);
      }
      __syncthreads();
      if(tid < Vn){
        const float lv = lg_s[tid];
        float mv = lv; int mi = tid;
#pragma unroll
        for(int off=1; off<64; off<<=1){
          float ov = __shfl_xor(mv, off);
          int   oi = __shfl_xor(mi, off);
          if(ov > mv || (ov == mv && oi < mi)){ mv = ov; mi = oi; }
        }
        float se = expf(lv - mv);
#pragma unroll
        for(int off=1; off<64; off<<=1) se += __shfl_xor(se, off);
        if(ts == 0) out[((size_t)(s-1)*Bn + b)*Vn + tid] = f2bf(lv - mv - logf(se));
        if(tid == 0) i_s[0] = mi;
      }
      __syncthreads();
    } else {
      ctx_s[tid] = bfu(lf[(size_t)b*Tn*Dn + tid]);
      __syncthreads();
    }

    if(s == Sn) break;

    {
      const int u  = tid >> 3;
      const int ks = tid & 7;
      const int uu = ts*64 + u;
      const unsigned short* wi0 = wih + (size_t)(       uu)*KIH + 64 + ks*64;
      const unsigned short* wi1 = wih + (size_t)(  Hn + uu)*KIH + 64 + ks*64;
      const unsigned short* wi2 = wih + (size_t)(2*Hn + uu)*KIH + 64 + ks*64;
      const unsigned short* wi3 = wih + (size_t)(3*Hn + uu)*KIH + 64 + ks*64;
      const unsigned short* wh0 = whh + (size_t)(       uu)*Hn + ks*64;
      const unsigned short* wh1 = whh + (size_t)(  Hn + uu)*Hn + ks*64;
      const unsigned short* wh2 = whh + (size_t)(2*Hn + uu)*Hn + ks*64;
      const unsigned short* wh3 = whh + (size_t)(3*Hn + uu)*Hn + ks*64;
      const float4* xc = (const float4*)(ctx_s + ks*64);
      const float4* xh4 = (const float4*)(h_s   + ks*64);
      float a0=0.f,a1=0.f,a2=0.f,a3=0.f;
#pragma unroll
      for(int i=0;i<8;i++){
        float4 p0 = xc[2*i], p1 = xc[2*i+1];
        a0 += dot8(ld8(wi0+8*i), p0, p1);
        a1 += dot8(ld8(wi1+8*i), p0, p1);
        a2 += dot8(ld8(wi2+8*i), p0, p1);
        a3 += dot8(ld8(wi3+8*i), p0, p1);
      }
#pragma unroll
      for(int i=0;i<8;i++){
        float4 p0 = xh4[2*i], p1 = xh4[2*i+1];
        a0 += dot8(ld8(wh0+8*i), p0, p1);
        a1 += dot8(ld8(wh1+8*i), p0, p1);
        a2 += dot8(ld8(wh2+8*i), p0, p1);
        a3 += dot8(ld8(wh3+8*i), p0, p1);
      }
#pragma unroll
      for(int off=1; off<8; off<<=1){
        a0 += __shfl_xor(a0, off);
        a1 += __shfl_xor(a1, off);
        a2 += __shfl_xor(a2, off);
        a3 += __shfl_xor(a3, off);
      }
      if(ks == 0){
        const int pidx = i_s[0];
        const int r0 = uu, r1 = Hn+uu, r2 = 2*Hn+uu, r3 = 3*Hn+uu;
        float gi = a0 + bfu(wih[(size_t)r0*KIH + pidx]) + bfu(bih[r0]) + bfu(bhh[r0]);
        float gf = a1 + bfu(wih[(size_t)r1*KIH + pidx]) + bfu(bih[r1]) + bfu(bhh[r1]);
        float gg = a2 + bfu(wih[(size_t)r2*KIH + pidx]) + bfu(bih[r2]) + bfu(bhh[r2]);
        float go = a3 + bfu(wih[(size_t)r3*KIH + pidx]) + bfu(bih[r3]) + bfu(bhh[r3]);
        gi = sigm(gi); gf = sigm(gf); gg = tnh(gg); go = sigm(go);
        float c = gf*c_s[u] + gi*gg;
        c_s[u] = c;
        aput(&hbuf[uu], go * tnh(c));
      }
    }
    gbar8(bar);

    h_s[tid] = aget(&hbuf[tid]);
    __syncthreads();
    {
      const int t2 = tid >> 3;
      const int q  = tid & 7;
      const float4* hq = (const float4*)(h_s + q*64);
      float ea=0.f, eb=0.f;
      const unsigned short* la = lf_s + (size_t)(2*t2  )*Dn + q*64;
      const unsigned short* lb = lf_s + (size_t)(2*t2+1)*Dn + q*64;
#pragma unroll
      for(int i=0;i<8;i++){
        float4 p0 = hq[2*i], p1 = hq[2*i+1];
        ea += dot8(ld8(la+8*i), p0, p1);
        eb += dot8(ld8(lb+8*i), p0, p1);
      }
#pragma unroll
      for(int off=1; off<8; off<<=1){ ea += __shfl_xor(ea,off); eb += __shfl_xor(eb,off); }
      if(q==0){ e_s[2*t2] = ea; e_s[2*t2+1] = eb; }
    }
    __syncthreads();
    if(tid < 64){
      float v = fmaxf(e_s[tid], e_s[tid+64]);
#pragma unroll
      for(int off=1; off<64; off<<=1) v = fmaxf(v, __shfl_xor(v,off));
      if(tid==0) red_s[10] = v;
    }
    __syncthreads();
    if(tid < TT) p_s[tid] = expf(e_s[tid] - red_s[10]);
    __syncthreads();
    if(tid < 64){
      float v = p_s[tid] + p_s[tid+64];
#pragma unroll
      for(int off=1; off<64; off<<=1) v += __shfl_xor(v,off);
      if(tid==0){ aput(&mstB[ts], red_s[10]); aput(&lstB[ts], v); }
    }
    {
      float acc = 0.f;
      const unsigned short* col = lf_s + tid;
#pragma unroll 4
      for(int t=0;t<TT;t++) acc += p_s[t] * bfu(col[(size_t)t*Dn]);
      aput(&ctxpB[(size_t)ts*Dn + tid], acc);
    }
    gbar8(bar);
  }
}

extern "C" void kernel_launch(void* const* d_in, const int* in_sizes, int n_in,
                              void* d_out, int out_size, void* d_ws, size_t ws_size,
                              hipStream_t stream) {
  (void)in_sizes; (void)n_in; (void)out_size; (void)ws_size;
  float* ws = (float*)d_ws;

  hipFuncSetAttribute(reinterpret_cast<const void*>(&speller_v3),
                      hipFuncAttributeMaxDynamicSharedMemorySize, LDS_BYTES);
  hipFuncSetAttribute(reinterpret_cast<const void*>(&speller_bf16),
                      hipFuncAttributeMaxDynamicSharedMemorySize, LDS_BYTES);
  // barrier + flag live in the first 4 KB (d_ws is poisoned before every launch)
  hipMemsetAsync(d_ws, 0, 4096, stream);
  dtype_probe<<<dim3(1), dim3(64), 0, stream>>>((const unsigned short*)d_in[3],
                                                (unsigned int*)d_ws + WS_FLAG);
  speller_v3<<<dim3(NBLK), dim3(NTHREADS), LDS_BYTES, stream>>>(
      (const float*)d_in[0], (const float*)d_in[1], (const float*)d_in[2],
      (const float*)d_in[3], (const float*)d_in[4], (const float*)d_in[5],
      (const float*)d_in[6], (float*)d_out, ws);
  speller_bf16<<<dim3(NBLK), dim3(NTHREADS), LDS_BYTES, stream>>>(
      (const unsigned short*)d_in[0], (const unsigned short*)d_in[1],
      (const unsigned short*)d_in[2], (const unsigned short*)d_in[3],
      (const unsigned short*)d_in[4], (const unsigned short*)d_in[5],
      (const unsigned short*)d_in[6], (unsigned short*)d_out, ws);
}

// Round 5
// 8282.470 us; speedup vs baseline: 2.4840x; 1.0989x over previous
//
#include <hip/hip_runtime.h>

// Problem constants
#define Bn 32
#define Tn 1024
#define Dn 512
#define Hn 512
#define Vn 64
#define Sn 128
#define NTS 8          // t-slices per batch
#define TT 128         // T per block (attention role)
#define NTHREADS 512
#define KIH 576        // W_ih cols (V + H)
#define NBLK 256

// LDS: 131072 (tile) + 9248 (scratch incl. wow_s) = 140320 -> 143360 (1 blk/CU)
#define LDS_BYTES 143360
#define OUT_ATT ((size_t)Sn * Bn * Vn)

// ws u32-index layout, first 4KB (memset to 0 each launch):
//   [g*16 + 0]  : global-barrier arrival counter for group g (monotonic)
//   [g*16 + 4,5]: E->C group barrier (arrivals, gen) for group g
//   [g*16 + 8]  : mirrored global generation for group g (leader-written)
//   [512]       : dtype flag (probe)
//   [576]       : global generation flag (master-written)
// ws float-index layout (v4 kernel data):
#define WS_XCTX  1024     // [32][512]  ctx(s-1)
#define WS_XH    17408    // [2][32][512] h double-buffered by step parity
#define WS_LGP   50176    // [32][64][8] logits partials
#define WS_MST   66560    // [32][8]
#define WS_LST   66816    // [32][8]
#define WS_CTXP  67072    // [32][8][512]

struct F8 { float4 a, b; };

__device__ __forceinline__ float bfu(unsigned short u){ return __uint_as_float(((unsigned int)u)<<16); }
__device__ __forceinline__ float bflo(unsigned int u){ return __uint_as_float(u<<16); }
__device__ __forceinline__ float bfhi(unsigned int u){ return __uint_as_float(u & 0xffff0000u); }
__device__ __forceinline__ unsigned short f2bf(float f){
  unsigned int x = __float_as_uint(f);
  return (unsigned short)((x + 0x7fffu + ((x>>16)&1u)) >> 16);   // RNE
}
__device__ __forceinline__ F8 ld8(const unsigned short* p){
  uint4 q = *(const uint4*)p;
  F8 r;
  r.a = make_float4(bflo(q.x), bfhi(q.x), bflo(q.y), bfhi(q.y));
  r.b = make_float4(bflo(q.z), bfhi(q.z), bflo(q.w), bfhi(q.w));
  return r;
}
__device__ __forceinline__ F8 ld8(const float* p){
  F8 r; r.a = *(const float4*)p; r.b = *(const float4*)(p+4); return r;
}
__device__ __forceinline__ float dot8(F8 w, float4 a, float4 b){
  return w.a.x*a.x + w.a.y*a.y + w.a.z*a.z + w.a.w*a.w
       + w.b.x*b.x + w.b.y*b.y + w.b.z*b.z + w.b.w*b.w;
}
__device__ __forceinline__ float dot64g(const unsigned short* __restrict__ w, const float* x){
  const float4* x4 = (const float4*)x;
  float acc = 0.f;
#pragma unroll
  for(int i=0;i<8;i++) acc += dot8(ld8(w+8*i), x4[2*i], x4[2*i+1]);
  return acc;
}
__device__ __forceinline__ float sigm(float x){
  x = fminf(fmaxf(x, -30.f), 30.f); return 1.f/(1.f + expf(-x));
}
__device__ __forceinline__ float tnh(float x){
  return tanhf(fminf(fmaxf(x, -20.f), 20.f));
}

// ---- relaxed agent-scope atomics (write-through to the coherence point) ----
__device__ __forceinline__ void aput(float* p, float v){
  __hip_atomic_store(p, v, __ATOMIC_RELAXED, __HIP_MEMORY_SCOPE_AGENT);
}
__device__ __forceinline__ float aget(const float* p){
  return __hip_atomic_load(p, __ATOMIC_RELAXED, __HIP_MEMORY_SCOPE_AGENT);
}
__device__ __forceinline__ unsigned int uget(const unsigned int* p){
  return __hip_atomic_load(p, __ATOMIC_RELAXED, __HIP_MEMORY_SCOPE_AGENT);
}

// ---- two-level global barrier (R5): distributed arrivals, fan-out release ----
// Arrivals: 8 RMWs per group line (32 lines in parallel) instead of 256 on one.
// Master (block 0, wave 0) lane-polls the 32 group counters, publishes gen at
// wsu[576]; group leaders mirror gen to wsu[g*16+8]; members poll only their
// group line. Every exit path does one ACQUIRE load (L1/L2 invalidate) so the
// subsequent PLAIN vectorized ws loads are coherent (R4-proven pattern).
__device__ __forceinline__ void gbar2(unsigned int* wsu, unsigned int ggen){
  asm volatile("s_waitcnt vmcnt(0)" ::: "memory");
  __syncthreads();
  const int tid = threadIdx.x;
  const int UP  = (int)blockIdx.x;
  const int grp = UP >> 3;
  if(UP == 0){
    if(tid < 64){
      if(tid == 0)
        __hip_atomic_fetch_add(&wsu[0], 1u, __ATOMIC_RELEASE, __HIP_MEMORY_SCOPE_AGENT);
      const unsigned int tgt = 8u*ggen;
      for(;;){
        unsigned int v = (tid < 32) ? uget(&wsu[tid*16]) : tgt;
        if(__all(v >= tgt)) break;
        __builtin_amdgcn_s_sleep(2);
      }
      if(tid == 0){
        __hip_atomic_store(&wsu[576], ggen, __ATOMIC_RELEASE, __HIP_MEMORY_SCOPE_AGENT);
        __hip_atomic_store(&wsu[8],   ggen, __ATOMIC_RELEASE, __HIP_MEMORY_SCOPE_AGENT);
        unsigned int x = __hip_atomic_load(&wsu[576], __ATOMIC_ACQUIRE, __HIP_MEMORY_SCOPE_AGENT);
        asm volatile("" :: "v"(x));
      }
    }
  } else if(tid == 0){
    __hip_atomic_fetch_add(&wsu[grp*16], 1u, __ATOMIC_RELEASE, __HIP_MEMORY_SCOPE_AGENT);
    if((UP & 7) == 0){   // group leader: fan-out the global gen to the group line
      while(uget(&wsu[576]) < ggen) __builtin_amdgcn_s_sleep(3);
      __hip_atomic_store(&wsu[grp*16 + 8], ggen, __ATOMIC_RELEASE, __HIP_MEMORY_SCOPE_AGENT);
    } else {
      while(uget(&wsu[grp*16 + 8]) < ggen) __builtin_amdgcn_s_sleep(3);
    }
    unsigned int x = __hip_atomic_load(&wsu[grp*16 + 8], __ATOMIC_ACQUIRE, __HIP_MEMORY_SCOPE_AGENT);
    asm volatile("" :: "v"(x));
  }
  __syncthreads();
  asm volatile("" ::: "memory");
}

// ---- 8-block group barrier (E->C; partials are group-local) — R1-proven ----
__device__ __forceinline__ void gbarE(unsigned int* line){
  asm volatile("s_waitcnt vmcnt(0)" ::: "memory");
  __syncthreads();
  if(threadIdx.x == 0){
    unsigned int g = uget(line+1);
    unsigned int p = __hip_atomic_fetch_add(line, 1u, __ATOMIC_RELEASE, __HIP_MEMORY_SCOPE_AGENT);
    if(p == g*8u + 7u){
      __hip_atomic_store(line+1, g+1u, __ATOMIC_RELEASE, __HIP_MEMORY_SCOPE_AGENT);
    } else {
      while(uget(line+1) == g) __builtin_amdgcn_s_sleep(2);
    }
    unsigned int x = __hip_atomic_load(line+1, __ATOMIC_ACQUIRE, __HIP_MEMORY_SCOPE_AGENT);
    asm volatile("" :: "v"(x));
  }
  __syncthreads();
  asm volatile("" ::: "memory");
}

// dtype probe: b_ih ~ N(0,0.01^2). flag: 1 = bf16, 2 = f32.
__global__ void dtype_probe(const unsigned short* __restrict__ b3, unsigned int* flag){
  const int t = threadIdx.x;
  bool ok = true;
#pragma unroll
  for(int i=0;i<8;i++){
    float v = bfu(b3[2*(t*8+i)]);
    ok = ok && (v == v) && (fabsf(v) < 0.5f);
  }
  unsigned long long m = __ballot(ok);
  if(t == 0)
    __hip_atomic_store(flag, (m == ~0ull) ? 1u : 2u, __ATOMIC_RELEASE, __HIP_MEMORY_SCOPE_AGENT);
}

// ============================================================================
// v4 (f32 inputs): R4 v3 compute structure (weights persist on-chip), with the
// single-counter global barrier replaced by the two-level gbar2, and the E->C
// barrier demoted to an 8-block group barrier (partials are group-local).
// ============================================================================
__global__ __launch_bounds__(NTHREADS, 2)
void speller_v3(const float* __restrict__ lf,  const float* __restrict__ wih,
                const float* __restrict__ whh, const float* __restrict__ bih,
                const float* __restrict__ bhh, const float* __restrict__ wout,
                const float* __restrict__ bout, float* __restrict__ out,
                float* __restrict__ ws)
{
  { unsigned int fl = __hip_atomic_load((unsigned int*)ws + 512, __ATOMIC_ACQUIRE, __HIP_MEMORY_SCOPE_AGENT);
    if(fl != 2u) return; }

  const int tid   = threadIdx.x;
  const int UP    = (int)blockIdx.x;      // unit-pair id; units 2UP, 2UP+1
  const int b_att = UP >> 3;              // attention batch
  const int ts    = UP & 7;               // attention t-slice
  const int w     = tid >> 6;             // wave 0..7
  const int lane  = tid & 63;

  extern __shared__ char smem[];
  float* tile   = (float*)smem;                 // [64][512] f32 swizzled LF rows 0..63
  float* epart  = (float*)(smem + 131072);      // [512]
  float* h_s    = epart + 512;                  // [512]
  float* e_s    = h_s + 512;                    // [128]
  float* p_s    = e_s + 128;                    // [128]
  float* red_s  = p_s + 128;                    // [32]
  float* pre_s  = red_s + 32;                   // [8][32] gate pre-activations
  float* ctxc_s = pre_s + 256;                  // [64] combined ctx chunk
  float* c_s    = ctxc_s + 64;                  // [64] cell state (bb*2+ul)
  float* bias_s = c_s + 64;                     // [8]
  float* bout_s = bias_s + 8;                   // [64]
  int*   pall_s = (int*)(bout_s + 64);          // [32] argmax per batch
  float* wow_s  = (float*)(pall_s + 32);        // [8][64] W_ih one-hot cols
  // end of scratch = 131072 + 9248 = 140320 <= LDS_BYTES

  unsigned int* wsu   = (unsigned int*)ws;
  unsigned int* eline = wsu + (size_t)b_att*16 + 4;
  float* xctx = ws + WS_XCTX;
  float* xh   = ws + WS_XH;
  float* lgp  = ws + WS_LGP;
  float* mst  = ws + WS_MST;
  float* lst  = ws + WS_LST;
  float* ctxp = ws + WS_CTXP;

  // this wave's gate-row: g = w>>1, unit = 2UP + (w&1)
  const int rw = (w>>1)*Hn + 2*UP + (w&1);

  // ---- persistent weight registers ----
  float4 wv0, wv1, wv2, wv3;      // 16-float gate-row chunk
  {
    const int k0 = 16*lane;
    const float* wp = (lane < 32) ? (wih + (size_t)rw*KIH + 64 + k0)
                                  : (whh + (size_t)rw*Hn + (k0 - 512));
    wv0 = *(const float4*)wp;     wv1 = *(const float4*)(wp+4);
    wv2 = *(const float4*)(wp+8); wv3 = *(const float4*)(wp+12);
  }
  float4 oh0, oh1, oc0, oc1;      // W_out K-slice: h-cols and ctx-cols
  {
    const int v = tid>>3, q = tid&7;
    const float* pH = wout + (size_t)v*(2*Hn) + ts*64 + q*8;
    const float* pC = pH + Hn;
    oh0 = *(const float4*)pH; oh1 = *(const float4*)(pH+4);
    oc0 = *(const float4*)pC; oc1 = *(const float4*)(pC+4);
  }

  // ---- LDS weight/aux fills ----
  {
    const int rr = tid>>6, cc = tid&63;
    const int r2 = (rr>>1)*Hn + 2*UP + (rr&1);
    wow_s[tid] = wih[(size_t)r2*KIH + cc];
  }
  if(tid < 8){ const int r2 = (tid>>1)*Hn + 2*UP + (tid&1); bias_s[tid] = bih[r2] + bhh[r2]; }
  if(tid < Vn) bout_s[tid] = bout[tid];
  if(tid < 64) c_s[tid] = 0.f;
  if(tid < 32) pall_s[tid] = 0;

  // ---- LF staging: rows 0..63 -> swizzled LDS; rows 64..127 -> registers ----
  float lfreg[64];
  {
    const float4* s4 = (const float4*)(lf + ((size_t)b_att*Tn + (size_t)ts*TT) * Dn);
    float4* d4 = (float4*)tile;
#pragma unroll
    for(int i=0;i<16;i++){
      const int f = tid + i*NTHREADS;       // float4 index in [0,8192)
      const int row = f >> 7, cc = f & 127;
      d4[(row << 7) | (cc ^ (row & 7))] = s4[f];
    }
    const float* lfg = lf + ((size_t)b_att*Tn + (size_t)ts*TT + 64) * Dn + tid;
#pragma unroll
    for(int j=0;j<64;j++) lfreg[j] = lfg[(size_t)j*Dn];
  }

  // ---- ws init: ctx(-1) = LF[:,0,:]; h(-1) = 0 (parity buffer 1) ----
  if(tid < 64){
    aput(&xctx[(size_t)b_att*Dn + ts*64 + tid], lf[(size_t)b_att*Tn*Dn + ts*64 + tid]);
    const int bb = tid>>1, ul = tid&1;
    aput(&xh[(size_t)Bn*Hn + (size_t)bb*Hn + 2*UP + ul], 0.f);
  }
  __syncthreads();
  unsigned int gg = 0;
  gbar2(wsu, ++gg);

  for(int s = 0; s <= Sn; ++s){
    // ================= G phase =================
    if(s > 0){   // logits(s-1) assembly + argmax (all blocks) + logp (writer blocks)
      for(int ii=0; ii<4; ++ii){
        const int bb = 4*w + ii;
        float lv = bout_s[lane];
        const float4* lp = (const float4*)(lgp + ((size_t)bb*Vn + lane)*8);
        float4 qa = lp[0], qb = lp[1];
        lv += qa.x+qa.y+qa.z+qa.w + qb.x+qb.y+qb.z+qb.w;
        float mv = lv; int mi = lane;
#pragma unroll
        for(int off=1; off<64; off<<=1){
          float ov = __shfl_xor(mv, off);
          int   oi = __shfl_xor(mi, off);
          if(ov > mv || (ov == mv && oi < mi)){ mv = ov; mi = oi; }
        }
        float se = expf(lv - mv);
#pragma unroll
        for(int off=1; off<64; off<<=1) se += __shfl_xor(se, off);
        if(lane == 0) pall_s[bb] = mi;
        if(UP == 8*bb) out[((size_t)(s-1)*Bn + bb)*Vn + lane] = lv - mv - logf(se);
      }
    }
    if(s == Sn) break;
    __syncthreads();   // pall_s ready

    // gates GEMM: wave = row, lane = 16-dim K chunk, loop over 32 batches
    {
      const float* xhR = xh + (size_t)(((s+1)&1))*Bn*Hn;   // h(s-1)
      const int k0 = 16*lane;
      for(int bb=0; bb<Bn; ++bb){
        const float* xp = (lane < 32) ? (xctx + (size_t)bb*Dn + k0)
                                      : (xhR  + (size_t)bb*Hn + (k0 - 512));
        float4 x0 = *(const float4*)xp,     x1 = *(const float4*)(xp+4),
               x2 = *(const float4*)(xp+8), x3 = *(const float4*)(xp+12);
        float acc = wv0.x*x0.x + wv0.y*x0.y + wv0.z*x0.z + wv0.w*x0.w
                  + wv1.x*x1.x + wv1.y*x1.y + wv1.z*x1.z + wv1.w*x1.w
                  + wv2.x*x2.x + wv2.y*x2.y + wv2.z*x2.z + wv2.w*x2.w
                  + wv3.x*x3.x + wv3.y*x3.y + wv3.z*x3.z + wv3.w*x3.w;
#pragma unroll
        for(int off=1; off<64; off<<=1) acc += __shfl_xor(acc, off);
        if(lane == 0) pre_s[w*Bn + bb] = acc;
      }
    }
    __syncthreads();
    if(tid < 64){   // c,h update: 2 units x 32 batches
      const int bb = tid>>1, ul = tid&1;
      const int pidx = pall_s[bb];
      float gi = sigm(pre_s[(0+ul)*Bn+bb] + wow_s[(0+ul)*64+pidx] + bias_s[0+ul]);
      float gf = sigm(pre_s[(2+ul)*Bn+bb] + wow_s[(2+ul)*64+pidx] + bias_s[2+ul]);
      float gg2 = tnh(pre_s[(4+ul)*Bn+bb] + wow_s[(4+ul)*64+pidx] + bias_s[4+ul]);
      float go = sigm(pre_s[(6+ul)*Bn+bb] + wow_s[(6+ul)*64+pidx] + bias_s[6+ul]);
      float c = gf*c_s[tid] + gi*gg2;
      c_s[tid] = c;
      aput(&xh[(size_t)(s&1)*Bn*Hn + (size_t)bb*Hn + 2*UP + ul], go*tnh(c));
    }
    gbar2(wsu, ++gg);

    // ================= E phase (attention) =================
    h_s[tid] = xh[(size_t)(s&1)*Bn*Hn + (size_t)b_att*Hn + tid];
    __syncthreads();
    {  // rows 0..63: one row per thread-group from swizzled tile
      const int t1 = tid >> 3, q = tid & 7, mm = t1 & 7;
      const float4* lrow = (const float4*)tile + (size_t)t1*128;
      const float4* hq = (const float4*)(h_s + q*64);
      float ea = 0.f;
#pragma unroll
      for(int i=0;i<8;i++){
        const int c0 = q*16 + 2*i;
        F8 wv; wv.a = lrow[c0 ^ mm]; wv.b = lrow[(c0+1) ^ mm];
        ea += dot8(wv, hq[2*i], hq[2*i+1]);
      }
#pragma unroll
      for(int off=1; off<8; off<<=1) ea += __shfl_xor(ea, off);
      if(q==0) e_s[t1] = ea;
    }
    {  // rows 64..127: butterfly over register columns
      const float h_own = h_s[tid];
      float mine = 0.f;
#pragma unroll
      for(int j=0;j<64;j++){
        float v = h_own * lfreg[j];
#pragma unroll
        for(int off=1; off<64; off<<=1) v += __shfl_xor(v, off);
        if(lane == j) mine = v;
      }
      epart[tid] = mine;
    }
    __syncthreads();
    if(tid < 64){
      float s2 = 0.f;
#pragma unroll
      for(int w2=0; w2<8; w2++) s2 += epart[(w2<<6) + tid];
      e_s[64 + tid] = s2;
      float v = fmaxf(e_s[tid], s2);
#pragma unroll
      for(int off=1; off<64; off<<=1) v = fmaxf(v, __shfl_xor(v,off));
      if(tid==0) red_s[10] = v;
    }
    __syncthreads();
    if(tid < TT) p_s[tid] = expf(e_s[tid] - red_s[10]);
    __syncthreads();
    if(tid < 64){
      float v = p_s[tid] + p_s[tid+64];
#pragma unroll
      for(int off=1; off<64; off<<=1) v += __shfl_xor(v,off);
      if(tid==0){
        aput(&mst[(size_t)b_att*NTS + ts], red_s[10]);
        aput(&lst[(size_t)b_att*NTS + ts], v);
      }
    }
    {  // ctx partial: thread owns one d, sweep 128 t's
      float acc = 0.f;
      const int cs = tid >> 2, cr = tid & 3;
#pragma unroll
      for(int t=0;t<64;t++)
        acc += p_s[t] * tile[(size_t)t*Dn + (((cs ^ (t&7))<<2) | cr)];
#pragma unroll
      for(int j=0;j<64;j++) acc += p_s[64+j] * lfreg[j];
      aput(&ctxp[((size_t)b_att*NTS + ts)*Dn + tid], acc);
    }
    gbarE(eline);

    // ================= C phase =================
    if(tid < NTS){
      red_s[16+tid] = mst[(size_t)b_att*NTS + tid];
      red_s[24+tid] = lst[(size_t)b_att*NTS + tid];
    }
    __syncthreads();
    if(tid == 0){
      float m = -3.0e38f;
#pragma unroll
      for(int j=0;j<NTS;j++) m = fmaxf(m, red_s[16+j]);
      float l = 0.f;
#pragma unroll
      for(int j=0;j<NTS;j++){ float fac = expf(red_s[16+j]-m); red_s[j]=fac; l += fac*red_s[24+j]; }
      red_s[8]=m; red_s[9]=l;
    }
    __syncthreads();
    {
      const float gm = red_s[8];
      const float gl = red_s[9];
      if(tid < TT)
        out[OUT_ATT + ((size_t)s*Bn + b_att)*Tn + (size_t)ts*TT + tid] = expf(e_s[tid] - gm)/gl;
      if(tid < 64){
        const int d = ts*64 + tid;
        float acc = 0.f;
#pragma unroll
        for(int j=0;j<NTS;j++) acc += red_s[j] * ctxp[((size_t)b_att*NTS + j)*Dn + d];
        const float cv = acc / gl;
        ctxc_s[tid] = cv;
        aput(&xctx[(size_t)b_att*Dn + d], cv);
      }
    }
    __syncthreads();
    {  // logits partial over this block's K chunk
      const int v = tid>>3, q = tid&7;
      const float4* hp = (const float4*)(h_s + ts*64 + q*8);
      const float4* cp = (const float4*)(ctxc_s + q*8);
      float4 ha = hp[0], hb = hp[1], ca = cp[0], cb = cp[1];
      float acc = oh0.x*ha.x + oh0.y*ha.y + oh0.z*ha.z + oh0.w*ha.w
                + oh1.x*hb.x + oh1.y*hb.y + oh1.z*hb.z + oh1.w*hb.w
                + oc0.x*ca.x + oc0.y*ca.y + oc0.z*ca.z + oc0.w*ca.w
                + oc1.x*cb.x + oc1.y*cb.y + oc1.z*cb.z + oc1.w*cb.w;
#pragma unroll
      for(int off=1; off<8; off<<=1) acc += __shfl_xor(acc, off);
      if(q == 0) aput(&lgp[((size_t)b_att*Vn + v)*8 + ts], acc);
    }
    gbar2(wsu, ++gg);
  }
}

// ============================================================================
// bf16-input fallback: round-1 structure (passed), per-batch barrier groups.
// ============================================================================
__device__ __forceinline__ void gbar8(unsigned int* bar){
  asm volatile("s_waitcnt vmcnt(0)" ::: "memory");
  __syncthreads();
  if(threadIdx.x==0){
    unsigned int g = uget(bar+1);
    unsigned int p = __hip_atomic_fetch_add(bar, 1u, __ATOMIC_RELAXED, __HIP_MEMORY_SCOPE_AGENT);
    if(p == g*NTS + (NTS-1)){
      __hip_atomic_store(bar+1, g+1u, __ATOMIC_RELAXED, __HIP_MEMORY_SCOPE_AGENT);
    } else {
      while(uget(bar+1) == g) __builtin_amdgcn_s_sleep(2);
    }
  }
  __syncthreads();
  asm volatile("" ::: "memory");
}

__global__ __launch_bounds__(NTHREADS, 2)
void speller_bf16(const unsigned short* __restrict__ lf, const unsigned short* __restrict__ wih,
                  const unsigned short* __restrict__ whh, const unsigned short* __restrict__ bih,
                  const unsigned short* __restrict__ bhh, const unsigned short* __restrict__ wout,
                  const unsigned short* __restrict__ bout, unsigned short* __restrict__ out,
                  float* __restrict__ ws)
{
  { unsigned int fl = __hip_atomic_load((unsigned int*)ws + 512, __ATOMIC_ACQUIRE, __HIP_MEMORY_SCOPE_AGENT);
    if(fl != 1u) return; }
  const int tid = threadIdx.x;
  const int b   = (int)(blockIdx.x >> 3);
  const int ts  = (int)(blockIdx.x & 7);

  extern __shared__ char smem[];
  unsigned short* lf_s = (unsigned short*)smem;           // [128][512] bf16
  float* h_s   = (float*)(smem + 131072);
  float* ctx_s = h_s + 512;
  float* e_s   = ctx_s + 512;
  float* p_s   = e_s + 128;
  float* lg_s  = p_s + 128;
  float* red_s = lg_s + 64;
  float* c_s   = red_s + 32;
  int*   i_s   = (int*)(c_s + 64);

  unsigned int* bar = (unsigned int*)ws + (size_t)b*16 + 4;
  float* hbuf = ws + 1024  + (size_t)b*Hn;
  float* mstB = ws + WS_MST + (size_t)b*NTS;
  float* lstB = ws + WS_LST + (size_t)b*NTS;
  float* ctxpB= ws + WS_CTXP + (size_t)b*NTS*Dn;

  {
    const uint4* s4 = (const uint4*)(lf + ((size_t)b*Tn + (size_t)ts*TT) * Dn);
    uint4* d4 = (uint4*)lf_s;
#pragma unroll
    for(int i=0;i<16;i++) d4[tid + i*NTHREADS] = s4[tid + i*NTHREADS];
  }
  h_s[tid] = 0.f;
  if(tid < 64) c_s[tid] = 0.f;
  if(tid == 0) i_s[0] = 0;
  __syncthreads();

  for(int s = 0; s <= Sn; ++s){
    if(s > 0){
      if(tid < NTS){ red_s[16+tid] = aget(&mstB[tid]); red_s[24+tid] = aget(&lstB[tid]); }
      __syncthreads();
      if(tid == 0){
        float m = -3.0e38f;
#pragma unroll
        for(int j=0;j<NTS;j++) m = fmaxf(m, red_s[16+j]);
        float l = 0.f;
#pragma unroll
        for(int j=0;j<NTS;j++){ float fac = expf(red_s[16+j]-m); red_s[j]=fac; l += fac*red_s[24+j]; }
        red_s[8]=m; red_s[9]=l;
      }
      __syncthreads();
      const float gm = red_s[8];
      const float gl = red_s[9];
      {
        float acc = 0.f;
#pragma unroll
        for(int j=0;j<NTS;j++) acc += red_s[j] * aget(&ctxpB[(size_t)j*Dn + tid]);
        ctx_s[tid] = acc / gl;
      }
      if(tid < TT)
        out[OUT_ATT + ((size_t)(s-1)*Bn + b)*Tn + (size_t)ts*TT + tid] = f2bf(expf(e_s[tid]-gm)/gl);
      __syncthreads();
      {
        const int j = tid >> 3, ks = tid & 7;
        const unsigned short* wr = wout + (size_t)j*(2*Hn) + ks*128;
        float acc;
        if(ks < 4) acc = dot64g(wr, h_s + ks*128)       + dot64g(wr+64, h_s + ks*128 + 64);
        else       acc = dot64g(wr, ctx_s + (ks-4)*128) + dot64g(wr+64, ctx_s + (ks-4)*128 + 64);
#pragma unroll
        for(int off=1; off<8; off<<=1) acc += __shfl_xor(acc, off);
        if(ks==0) lg_s[j] = acc + bfu(bout[j]);
      }
      __syncthreads();
      if(tid < Vn){
        const float lv = lg_s[tid];
        float mv = lv; int mi = tid;
#pragma unroll
        for(int off=1; off<64; off<<=1){
          float ov = __shfl_xor(mv, off);
          int   oi = __shfl_xor(mi, off);
          if(ov > mv || (ov == mv && oi < mi)){ mv = ov; mi = oi; }
        }
        float se = expf(lv - mv);
#pragma unroll
        for(int off=1; off<64; off<<=1) se += __shfl_xor(se, off);
        if(ts == 0) out[((size_t)(s-1)*Bn + b)*Vn + tid] = f2bf(lv - mv - logf(se));
        if(tid == 0) i_s[0] = mi;
      }
      __syncthreads();
    } else {
      ctx_s[tid] = bfu(lf[(size_t)b*Tn*Dn + tid]);
      __syncthreads();
    }

    if(s == Sn) break;

    {
      const int u  = tid >> 3;
      const int ks = tid & 7;
      const int uu = ts*64 + u;
      const unsigned short* wi0 = wih + (size_t)(       uu)*KIH + 64 + ks*64;
      const unsigned short* wi1 = wih + (size_t)(  Hn + uu)*KIH + 64 + ks*64;
      const unsigned short* wi2 = wih + (size_t)(2*Hn + uu)*KIH + 64 + ks*64;
      const unsigned short* wi3 = wih + (size_t)(3*Hn + uu)*KIH + 64 + ks*64;
      const unsigned short* wh0 = whh + (size_t)(       uu)*Hn + ks*64;
      const unsigned short* wh1 = whh + (size_t)(  Hn + uu)*Hn + ks*64;
      const unsigned short* wh2 = whh + (size_t)(2*Hn + uu)*Hn + ks*64;
      const unsigned short* wh3 = whh + (size_t)(3*Hn + uu)*Hn + ks*64;
      const float4* xc = (const float4*)(ctx_s + ks*64);
      const float4* xh4 = (const float4*)(h_s   + ks*64);
      float a0=0.f,a1=0.f,a2=0.f,a3=0.f;
#pragma unroll
      for(int i=0;i<8;i++){
        float4 p0 = xc[2*i], p1 = xc[2*i+1];
        a0 += dot8(ld8(wi0+8*i), p0, p1);
        a1 += dot8(ld8(wi1+8*i), p0, p1);
        a2 += dot8(ld8(wi2+8*i), p0, p1);
        a3 += dot8(ld8(wi3+8*i), p0, p1);
      }
#pragma unroll
      for(int i=0;i<8;i++){
        float4 p0 = xh4[2*i], p1 = xh4[2*i+1];
        a0 += dot8(ld8(wh0+8*i), p0, p1);
        a1 += dot8(ld8(wh1+8*i), p0, p1);
        a2 += dot8(ld8(wh2+8*i), p0, p1);
        a3 += dot8(ld8(wh3+8*i), p0, p1);
      }
#pragma unroll
      for(int off=1; off<8; off<<=1){
        a0 += __shfl_xor(a0, off);
        a1 += __shfl_xor(a1, off);
        a2 += __shfl_xor(a2, off);
        a3 += __shfl_xor(a3, off);
      }
      if(ks == 0){
        const int pidx = i_s[0];
        const int r0 = uu, r1 = Hn+uu, r2 = 2*Hn+uu, r3 = 3*Hn+uu;
        float gi = a0 + bfu(wih[(size_t)r0*KIH + pidx]) + bfu(bih[r0]) + bfu(bhh[r0]);
        float gf = a1 + bfu(wih[(size_t)r1*KIH + pidx]) + bfu(bih[r1]) + bfu(bhh[r1]);
        float gg = a2 + bfu(wih[(size_t)r2*KIH + pidx]) + bfu(bih[r2]) + bfu(bhh[r2]);
        float go = a3 + bfu(wih[(size_t)r3*KIH + pidx]) + bfu(bih[r3]) + bfu(bhh[r3]);
        gi = sigm(gi); gf = sigm(gf); gg = tnh(gg); go = sigm(go);
        float c = gf*c_s[u] + gi*gg;
        c_s[u] = c;
        aput(&hbuf[uu], go * tnh(c));
      }
    }
    gbar8(bar);

    h_s[tid] = aget(&hbuf[tid]);
    __syncthreads();
    {
      const int t2 = tid >> 3;
      const int q  = tid & 7;
      const float4* hq = (const float4*)(h_s + q*64);
      float ea=0.f, eb=0.f;
      const unsigned short* la = lf_s + (size_t)(2*t2  )*Dn + q*64;
      const unsigned short* lb = lf_s + (size_t)(2*t2+1)*Dn + q*64;
#pragma unroll
      for(int i=0;i<8;i++){
        float4 p0 = hq[2*i], p1 = hq[2*i+1];
        ea += dot8(ld8(la+8*i), p0, p1);
        eb += dot8(ld8(lb+8*i), p0, p1);
      }
#pragma unroll
      for(int off=1; off<8; off<<=1){ ea += __shfl_xor(ea,off); eb += __shfl_xor(eb,off); }
      if(q==0){ e_s[2*t2] = ea; e_s[2*t2+1] = eb; }
    }
    __syncthreads();
    if(tid < 64){
      float v = fmaxf(e_s[tid], e_s[tid+64]);
#pragma unroll
      for(int off=1; off<64; off<<=1) v = fmaxf(v, __shfl_xor(v,off));
      if(tid==0) red_s[10] = v;
    }
    __syncthreads();
    if(tid < TT) p_s[tid] = expf(e_s[tid] - red_s[10]);
    __syncthreads();
    if(tid < 64){
      float v = p_s[tid] + p_s[tid+64];
#pragma unroll
      for(int off=1; off<64; off<<=1) v += __shfl_xor(v,off);
      if(tid==0){ aput(&mstB[ts], red_s[10]); aput(&lstB[ts], v); }
    }
    {
      float acc = 0.f;
      const unsigned short* col = lf_s + tid;
#pragma unroll 4
      for(int t=0;t<TT;t++) acc += p_s[t] * bfu(col[(size_t)t*Dn]);
      aput(&ctxpB[(size_t)ts*Dn + tid], acc);
    }
    gbar8(bar);
  }
}

extern "C" void kernel_launch(void* const* d_in, const int* in_sizes, int n_in,
                              void* d_out, int out_size, void* d_ws, size_t ws_size,
                              hipStream_t stream) {
  (void)in_sizes; (void)n_in; (void)out_size; (void)ws_size;
  float* ws = (float*)d_ws;

  hipFuncSetAttribute(reinterpret_cast<const void*>(&speller_v3),
                      hipFuncAttributeMaxDynamicSharedMemorySize, LDS_BYTES);
  hipFuncSetAttribute(reinterpret_cast<const void*>(&speller_bf16),
                      hipFuncAttributeMaxDynamicSharedMemorySize, LDS_BYTES);
  // barriers + flags live in the first 4 KB (d_ws is poisoned before every launch)
  hipMemsetAsync(d_ws, 0, 4096, stream);
  dtype_probe<<<dim3(1), dim3(64), 0, stream>>>((const unsigned short*)d_in[3],
                                                (unsigned int*)d_ws + 512);
  speller_v3<<<dim3(NBLK), dim3(NTHREADS), LDS_BYTES, stream>>>(
      (const float*)d_in[0], (const float*)d_in[1], (const float*)d_in[2],
      (const float*)d_in[3], (const float*)d_in[4], (const float*)d_in[5],
      (const float*)d_in[6], (float*)d_out, ws);
  speller_bf16<<<dim3(NBLK), dim3(NTHREADS), LDS_BYTES, stream>>>(
      (const unsigned short*)d_in[0], (const unsigned short*)d_in[1],
      (const unsigned short*)d_in[2], (const unsigned short*)d_in[3],
      (const unsigned short*)d_in[4], (const unsigned short*)d_in[5],
      (const unsigned short*)d_in[6], (unsigned short*)d_out, ws);
}

// Round 6
// 6769.203 us; speedup vs baseline: 3.0393x; 1.2236x over previous
//
#include <hip/hip_runtime.h>

// Problem constants
#define Bn 32
#define Tn 1024
#define Dn 512
#define Hn 512
#define Vn 64
#define Sn 128
#define NTS 8          // t-slices per batch
#define TT 128         // T per block (attention role)
#define NTHREADS 512
#define KIH 576        // W_ih cols (V + H)
#define NBLK 256

// LDS: 131072 (tile) + 9248 (scratch incl. wow_s) = 140320 -> 143360 (1 blk/CU)
#define LDS_BYTES 143360
#define OUT_ATT ((size_t)Sn * Bn * Vn)

// ws u32-index layout, first 4KB (memset to 0 each launch):
//   [g*16 + 0]  : global-barrier arrival counter for group g (monotonic)
//   [g*16 + 4,5]: E->C group barrier (arrivals, gen) for group g
//   [g*16 + 8]  : global generation, broadcast by master (one store per line)
//   [512]       : dtype flag (probe)
// ws float-index layout:
#define WS_XCTX  1024     // [32][512]  ctx(s-1)
#define WS_XH    17408    // [2][32][512] h double-buffered by step parity
#define WS_LGP   50176    // [32][64][8] logits partials
#define WS_MST   66560    // [32][8]
#define WS_LST   66816    // [32][8]
#define WS_CTXP  67072    // [32][8][512]

struct F8 { float4 a, b; };

__device__ __forceinline__ float bfu(unsigned short u){ return __uint_as_float(((unsigned int)u)<<16); }
__device__ __forceinline__ float bflo(unsigned int u){ return __uint_as_float(u<<16); }
__device__ __forceinline__ float bfhi(unsigned int u){ return __uint_as_float(u & 0xffff0000u); }
__device__ __forceinline__ unsigned short f2bf(float f){
  unsigned int x = __float_as_uint(f);
  return (unsigned short)((x + 0x7fffu + ((x>>16)&1u)) >> 16);   // RNE
}
__device__ __forceinline__ F8 ld8(const unsigned short* p){
  uint4 q = *(const uint4*)p;
  F8 r;
  r.a = make_float4(bflo(q.x), bfhi(q.x), bflo(q.y), bfhi(q.y));
  r.b = make_float4(bflo(q.z), bfhi(q.z), bflo(q.w), bfhi(q.w));
  return r;
}
__device__ __forceinline__ F8 ld8(const float* p){
  F8 r; r.a = *(const float4*)p; r.b = *(const float4*)(p+4); return r;
}
__device__ __forceinline__ float dot8(F8 w, float4 a, float4 b){
  return w.a.x*a.x + w.a.y*a.y + w.a.z*a.z + w.a.w*a.w
       + w.b.x*b.x + w.b.y*b.y + w.b.z*b.z + w.b.w*b.w;
}
__device__ __forceinline__ float dot64g(const unsigned short* __restrict__ w, const float* x){
  const float4* x4 = (const float4*)x;
  float acc = 0.f;
#pragma unroll
  for(int i=0;i<8;i++) acc += dot8(ld8(w+8*i), x4[2*i], x4[2*i+1]);
  return acc;
}
__device__ __forceinline__ float sigm(float x){
  x = fminf(fmaxf(x, -30.f), 30.f); return 1.f/(1.f + expf(-x));
}
__device__ __forceinline__ float tnh(float x){
  return tanhf(fminf(fmaxf(x, -20.f), 20.f));
}

// Recursive-halving reduce-scatter round: lane keeps the half of its value-set
// selected by `hi`, receives the partner's matching half, and adds.
// After rounds off=32..2 plus a final pair-add, lane l holds the full 64-lane
// sum of value j=(l>>1) (32-value case) / j=l (64-value case, rounds 32..1).
template<int N>
__device__ __forceinline__ void rs_round(float* a, int off, bool hi){
#pragma unroll
  for(int i=0;i<N;i++){
    float send = hi ? a[i]   : a[i+N];
    float keep = hi ? a[i+N] : a[i];
    float recv = __shfl_xor(send, off);
    a[i] = keep + recv;
  }
}
__device__ __forceinline__ void rs32(float* a, int lane){
  rs_round<16>(a, 32, (lane&32)!=0);
  rs_round< 8>(a, 16, (lane&16)!=0);
  rs_round< 4>(a,  8, (lane& 8)!=0);
  rs_round< 2>(a,  4, (lane& 4)!=0);
  rs_round< 1>(a,  2, (lane& 2)!=0);
  a[0] += __shfl_xor(a[0], 1);     // both lanes of the pair hold sum for j=l>>1
}

// ---- relaxed agent-scope atomics (write-through to the coherence point) ----
__device__ __forceinline__ void aput(float* p, float v){
  __hip_atomic_store(p, v, __ATOMIC_RELAXED, __HIP_MEMORY_SCOPE_AGENT);
}
__device__ __forceinline__ float aget(const float* p){
  return __hip_atomic_load(p, __ATOMIC_RELAXED, __HIP_MEMORY_SCOPE_AGENT);
}
__device__ __forceinline__ unsigned int uget(const unsigned int* p){
  return __hip_atomic_load(p, __ATOMIC_RELAXED, __HIP_MEMORY_SCOPE_AGENT);
}

// ---- flattened two-level global barrier (R6) ----
// Arrivals distributed over 32 group lines (8 RMWs each). Master (block 0,
// wave 0) gathers the 32 counters with ONE vector load per poll, then
// broadcasts the generation to all 32 group lines with ONE 32-lane vector
// store (no leader-mirror hop). Members poll only their group line. One
// ACQUIRE load per block at exit keeps subsequent plain loads coherent.
__device__ __forceinline__ void gbar2(unsigned int* wsu, unsigned int ggen){
  asm volatile("s_waitcnt vmcnt(0)" ::: "memory");
  __syncthreads();
  const int tid = threadIdx.x;
  const int UP  = (int)blockIdx.x;
  const int grp = UP >> 3;
  if(UP == 0){
    if(tid < 64){
      if(tid == 0)
        __hip_atomic_fetch_add(&wsu[0], 1u, __ATOMIC_RELEASE, __HIP_MEMORY_SCOPE_AGENT);
      const unsigned int tgt = 8u*ggen;
      for(;;){
        unsigned int v = (tid < 32) ? uget(&wsu[tid*16]) : tgt;
        if(__all(v >= tgt)) break;
        __builtin_amdgcn_s_sleep(1);
      }
      if(tid < 32)
        __hip_atomic_store(&wsu[tid*16 + 8], ggen, __ATOMIC_RELEASE, __HIP_MEMORY_SCOPE_AGENT);
    }
  } else if(tid == 0){
    __hip_atomic_fetch_add(&wsu[grp*16], 1u, __ATOMIC_RELEASE, __HIP_MEMORY_SCOPE_AGENT);
    while(uget(&wsu[grp*16 + 8]) < ggen) __builtin_amdgcn_s_sleep(1);
  }
  if(tid == 0){
    unsigned int x = __hip_atomic_load(&wsu[grp*16 + 8], __ATOMIC_ACQUIRE, __HIP_MEMORY_SCOPE_AGENT);
    asm volatile("" :: "v"(x));
  }
  __syncthreads();
  asm volatile("" ::: "memory");
}

// ---- 8-block group barrier (E->C; partials are group-local) — R1-proven ----
__device__ __forceinline__ void gbarE(unsigned int* line){
  asm volatile("s_waitcnt vmcnt(0)" ::: "memory");
  __syncthreads();
  if(threadIdx.x == 0){
    unsigned int g = uget(line+1);
    unsigned int p = __hip_atomic_fetch_add(line, 1u, __ATOMIC_RELEASE, __HIP_MEMORY_SCOPE_AGENT);
    if(p == g*8u + 7u){
      __hip_atomic_store(line+1, g+1u, __ATOMIC_RELEASE, __HIP_MEMORY_SCOPE_AGENT);
    } else {
      while(uget(line+1) == g) __builtin_amdgcn_s_sleep(1);
    }
    unsigned int x = __hip_atomic_load(line+1, __ATOMIC_ACQUIRE, __HIP_MEMORY_SCOPE_AGENT);
    asm volatile("" :: "v"(x));
  }
  __syncthreads();
  asm volatile("" ::: "memory");
}

// dtype probe: b_ih ~ N(0,0.01^2). flag: 1 = bf16, 2 = f32.
__global__ void dtype_probe(const unsigned short* __restrict__ b3, unsigned int* flag){
  const int t = threadIdx.x;
  bool ok = true;
#pragma unroll
  for(int i=0;i<8;i++){
    float v = bfu(b3[2*(t*8+i)]);
    ok = ok && (v == v) && (fabsf(v) < 0.5f);
  }
  unsigned long long m = __ballot(ok);
  if(t == 0)
    __hip_atomic_store(flag, (m == ~0ull) ? 1u : 2u, __ATOMIC_RELEASE, __HIP_MEMORY_SCOPE_AGENT);
}

// ============================================================================
// v5 (f32 inputs): weights persist on-chip (R4 structure); reduce-scatter
// replaces shuffle butterflies in gates GEMV and E-phase register rows;
// launch_bounds(512,1) lifts the 128-VGPR cap (1 blk/CU is LDS-forced anyway).
// ============================================================================
__global__ __launch_bounds__(NTHREADS, 1)
void speller_v3(const float* __restrict__ lf,  const float* __restrict__ wih,
                const float* __restrict__ whh, const float* __restrict__ bih,
                const float* __restrict__ bhh, const float* __restrict__ wout,
                const float* __restrict__ bout, float* __restrict__ out,
                float* __restrict__ ws)
{
  { unsigned int fl = __hip_atomic_load((unsigned int*)ws + 512, __ATOMIC_ACQUIRE, __HIP_MEMORY_SCOPE_AGENT);
    if(fl != 2u) return; }

  const int tid   = threadIdx.x;
  const int UP    = (int)blockIdx.x;      // unit-pair id; units 2UP, 2UP+1
  const int b_att = UP >> 3;              // attention batch
  const int ts    = UP & 7;               // attention t-slice
  const int w     = tid >> 6;             // wave 0..7
  const int lane  = tid & 63;

  extern __shared__ char smem[];
  float* tile   = (float*)smem;                 // [64][512] f32 swizzled LF rows 0..63
  float* epart  = (float*)(smem + 131072);      // [512]
  float* h_s    = epart + 512;                  // [512]
  float* e_s    = h_s + 512;                    // [128]
  float* p_s    = e_s + 128;                    // [128]
  float* red_s  = p_s + 128;                    // [32]
  float* pre_s  = red_s + 32;                   // [8][32] gate pre-activations
  float* ctxc_s = pre_s + 256;                  // [64] combined ctx chunk
  float* c_s    = ctxc_s + 64;                  // [64] cell state (bb*2+ul)
  float* bias_s = c_s + 64;                     // [8]
  float* bout_s = bias_s + 8;                   // [64]
  int*   pall_s = (int*)(bout_s + 64);          // [32] argmax per batch
  float* wow_s  = (float*)(pall_s + 32);        // [8][64] W_ih one-hot cols
  // end of scratch = 131072 + 9248 = 140320 <= LDS_BYTES

  unsigned int* wsu   = (unsigned int*)ws;
  unsigned int* eline = wsu + (size_t)b_att*16 + 4;
  float* xctx = ws + WS_XCTX;
  float* xh   = ws + WS_XH;
  float* lgp  = ws + WS_LGP;
  float* mst  = ws + WS_MST;
  float* lst  = ws + WS_LST;
  float* ctxp = ws + WS_CTXP;

  // this wave's gate-row: g = w>>1, unit = 2UP + (w&1)
  const int rw = (w>>1)*Hn + 2*UP + (w&1);

  // ---- persistent weight registers ----
  float4 wv0, wv1, wv2, wv3;      // 16-float gate-row chunk
  {
    const int k0 = 16*lane;
    const float* wp = (lane < 32) ? (wih + (size_t)rw*KIH + 64 + k0)
                                  : (whh + (size_t)rw*Hn + (k0 - 512));
    wv0 = *(const float4*)wp;     wv1 = *(const float4*)(wp+4);
    wv2 = *(const float4*)(wp+8); wv3 = *(const float4*)(wp+12);
  }
  float4 oh0, oh1, oc0, oc1;      // W_out K-slice: h-cols and ctx-cols
  {
    const int v = tid>>3, q = tid&7;
    const float* pH = wout + (size_t)v*(2*Hn) + ts*64 + q*8;
    const float* pC = pH + Hn;
    oh0 = *(const float4*)pH; oh1 = *(const float4*)(pH+4);
    oc0 = *(const float4*)pC; oc1 = *(const float4*)(pC+4);
  }

  // ---- LDS weight/aux fills ----
  {
    const int rr = tid>>6, cc = tid&63;
    const int r2 = (rr>>1)*Hn + 2*UP + (rr&1);
    wow_s[tid] = wih[(size_t)r2*KIH + cc];
  }
  if(tid < 8){ const int r2 = (tid>>1)*Hn + 2*UP + (tid&1); bias_s[tid] = bih[r2] + bhh[r2]; }
  if(tid < Vn) bout_s[tid] = bout[tid];
  if(tid < 64) c_s[tid] = 0.f;
  if(tid < 32) pall_s[tid] = 0;

  // ---- LF staging: rows 0..63 -> swizzled LDS; rows 64..127 -> registers ----
  float lfreg[64];
  {
    const float4* s4 = (const float4*)(lf + ((size_t)b_att*Tn + (size_t)ts*TT) * Dn);
    float4* d4 = (float4*)tile;
#pragma unroll
    for(int i=0;i<16;i++){
      const int f = tid + i*NTHREADS;       // float4 index in [0,8192)
      const int row = f >> 7, cc = f & 127;
      d4[(row << 7) | (cc ^ (row & 7))] = s4[f];
    }
    const float* lfg = lf + ((size_t)b_att*Tn + (size_t)ts*TT + 64) * Dn + tid;
#pragma unroll
    for(int j=0;j<64;j++) lfreg[j] = lfg[(size_t)j*Dn];
  }

  // ---- ws init: ctx(-1) = LF[:,0,:]; h(-1) = 0 (parity buffer 1) ----
  if(tid < 64){
    aput(&xctx[(size_t)b_att*Dn + ts*64 + tid], lf[(size_t)b_att*Tn*Dn + ts*64 + tid]);
    const int bb = tid>>1, ul = tid&1;
    aput(&xh[(size_t)Bn*Hn + (size_t)bb*Hn + 2*UP + ul], 0.f);
  }
  __syncthreads();
  unsigned int gg = 0;
  gbar2(wsu, ++gg);

  for(int s = 0; s <= Sn; ++s){
    // ================= G phase =================
    if(s > 0){   // logits(s-1) assembly + argmax (all blocks) + logp (writer blocks)
      for(int ii=0; ii<4; ++ii){
        const int bb = 4*w + ii;
        float lv = bout_s[lane];
        const float4* lp = (const float4*)(lgp + ((size_t)bb*Vn + lane)*8);
        float4 qa = lp[0], qb = lp[1];
        lv += qa.x+qa.y+qa.z+qa.w + qb.x+qb.y+qb.z+qb.w;
        float mv = lv; int mi = lane;
#pragma unroll
        for(int off=1; off<64; off<<=1){
          float ov = __shfl_xor(mv, off);
          int   oi = __shfl_xor(mi, off);
          if(ov > mv || (ov == mv && oi < mi)){ mv = ov; mi = oi; }
        }
        float se = expf(lv - mv);
#pragma unroll
        for(int off=1; off<64; off<<=1) se += __shfl_xor(se, off);
        if(lane == 0) pall_s[bb] = mi;
        if(UP == 8*bb) out[((size_t)(s-1)*Bn + bb)*Vn + lane] = lv - mv - logf(se);
      }
    }
    if(s == Sn) break;
    __syncthreads();   // pall_s ready

    // gates GEMV: wave = row, lane = 16-dim K chunk; pure FMA accumulation into
    // acc[32], then one reduce-scatter (32 shuffles vs 32x6 butterfly).
    {
      const float* xhR = xh + (size_t)(((s+1)&1))*Bn*Hn;   // h(s-1)
      const int k0 = 16*lane;
      const float* xbase = (lane < 32) ? (xctx + k0) : (xhR + (k0 - 512));
      float acc[Bn];
#pragma unroll
      for(int bb=0; bb<Bn; ++bb){
        const float4* xp = (const float4*)(xbase + (size_t)bb*Dn);
        float4 x0 = xp[0], x1 = xp[1], x2 = xp[2], x3 = xp[3];
        acc[bb] = wv0.x*x0.x + wv0.y*x0.y + wv0.z*x0.z + wv0.w*x0.w
                + wv1.x*x1.x + wv1.y*x1.y + wv1.z*x1.z + wv1.w*x1.w
                + wv2.x*x2.x + wv2.y*x2.y + wv2.z*x2.z + wv2.w*x2.w
                + wv3.x*x3.x + wv3.y*x3.y + wv3.z*x3.z + wv3.w*x3.w;
      }
      rs32(acc, lane);
      if((lane & 1) == 0) pre_s[w*Bn + (lane>>1)] = acc[0];
    }
    __syncthreads();
    if(tid < 64){   // c,h update: 2 units x 32 batches
      const int bb = tid>>1, ul = tid&1;
      const int pidx = pall_s[bb];
      float gi = sigm(pre_s[(0+ul)*Bn+bb] + wow_s[(0+ul)*64+pidx] + bias_s[0+ul]);
      float gf = sigm(pre_s[(2+ul)*Bn+bb] + wow_s[(2+ul)*64+pidx] + bias_s[2+ul]);
      float gg2 = tnh(pre_s[(4+ul)*Bn+bb] + wow_s[(4+ul)*64+pidx] + bias_s[4+ul]);
      float go = sigm(pre_s[(6+ul)*Bn+bb] + wow_s[(6+ul)*64+pidx] + bias_s[6+ul]);
      float c = gf*c_s[tid] + gi*gg2;
      c_s[tid] = c;
      aput(&xh[(size_t)(s&1)*Bn*Hn + (size_t)bb*Hn + 2*UP + ul], go*tnh(c));
    }
    gbar2(wsu, ++gg);

    // ================= E phase (attention) =================
    h_s[tid] = xh[(size_t)(s&1)*Bn*Hn + (size_t)b_att*Hn + tid];
    __syncthreads();
    {  // rows 0..63: one row per thread-group from swizzled tile
      const int t1 = tid >> 3, q = tid & 7, mm = t1 & 7;
      const float4* lrow = (const float4*)tile + (size_t)t1*128;
      const float4* hq = (const float4*)(h_s + q*64);
      float ea = 0.f;
#pragma unroll
      for(int i=0;i<8;i++){
        const int c0 = q*16 + 2*i;
        F8 wv; wv.a = lrow[c0 ^ mm]; wv.b = lrow[(c0+1) ^ mm];
        ea += dot8(wv, hq[2*i], hq[2*i+1]);
      }
#pragma unroll
      for(int off=1; off<8; off<<=1) ea += __shfl_xor(ea, off);
      if(q==0) e_s[t1] = ea;
    }
    {  // rows 64..127: reduce-scatter over register columns, two 32-row halves
      const float h_own = h_s[tid];
      float a[32];
#pragma unroll
      for(int j=0;j<32;j++) a[j] = h_own * lfreg[j];
      rs32(a, lane);
      if((lane & 1) == 0) epart[(w<<6) + (lane>>1)] = a[0];
#pragma unroll
      for(int j=0;j<32;j++) a[j] = h_own * lfreg[32+j];
      rs32(a, lane);
      if((lane & 1) == 0) epart[(w<<6) + 32 + (lane>>1)] = a[0];
    }
    __syncthreads();
    if(tid < 64){
      float s2 = 0.f;
#pragma unroll
      for(int w2=0; w2<8; w2++) s2 += epart[(w2<<6) + tid];
      e_s[64 + tid] = s2;
      float v = fmaxf(e_s[tid], s2);
#pragma unroll
      for(int off=1; off<64; off<<=1) v = fmaxf(v, __shfl_xor(v,off));
      if(tid==0) red_s[10] = v;
    }
    __syncthreads();
    if(tid < TT) p_s[tid] = expf(e_s[tid] - red_s[10]);
    __syncthreads();
    if(tid < 64){
      float v = p_s[tid] + p_s[tid+64];
#pragma unroll
      for(int off=1; off<64; off<<=1) v += __shfl_xor(v,off);
      if(tid==0){
        aput(&mst[(size_t)b_att*NTS + ts], red_s[10]);
        aput(&lst[(size_t)b_att*NTS + ts], v);
      }
    }
    {  // ctx partial: thread owns one d, sweep 128 t's
      float acc = 0.f;
      const int cs = tid >> 2, cr = tid & 3;
#pragma unroll
      for(int t=0;t<64;t++)
        acc += p_s[t] * tile[(size_t)t*Dn + (((cs ^ (t&7))<<2) | cr)];
#pragma unroll
      for(int j=0;j<64;j++) acc += p_s[64+j] * lfreg[j];
      aput(&ctxp[((size_t)b_att*NTS + ts)*Dn + tid], acc);
    }
    gbarE(eline);

    // ================= C phase =================
    if(tid < NTS){
      red_s[16+tid] = mst[(size_t)b_att*NTS + tid];
      red_s[24+tid] = lst[(size_t)b_att*NTS + tid];
    }
    __syncthreads();
    if(tid == 0){
      float m = -3.0e38f;
#pragma unroll
      for(int j=0;j<NTS;j++) m = fmaxf(m, red_s[16+j]);
      float l = 0.f;
#pragma unroll
      for(int j=0;j<NTS;j++){ float fac = expf(red_s[16+j]-m); red_s[j]=fac; l += fac*red_s[24+j]; }
      red_s[8]=m; red_s[9]=l;
    }
    __syncthreads();
    {
      const float gm = red_s[8];
      const float gl = red_s[9];
      if(tid < TT)
        out[OUT_ATT + ((size_t)s*Bn + b_att)*Tn + (size_t)ts*TT + tid] = expf(e_s[tid] - gm)/gl;
      if(tid < 64){
        const int d = ts*64 + tid;
        float acc = 0.f;
#pragma unroll
        for(int j=0;j<NTS;j++) acc += red_s[j] * ctxp[((size_t)b_att*NTS + j)*Dn + d];
        const float cv = acc / gl;
        ctxc_s[tid] = cv;
        aput(&xctx[(size_t)b_att*Dn + d], cv);
      }
    }
    __syncthreads();
    {  // logits partial over this block's K chunk
      const int v = tid>>3, q = tid&7;
      const float4* hp = (const float4*)(h_s + ts*64 + q*8);
      const float4* cp = (const float4*)(ctxc_s + q*8);
      float4 ha = hp[0], hb = hp[1], ca = cp[0], cb = cp[1];
      float acc = oh0.x*ha.x + oh0.y*ha.y + oh0.z*ha.z + oh0.w*ha.w
                + oh1.x*hb.x + oh1.y*hb.y + oh1.z*hb.z + oh1.w*hb.w
                + oc0.x*ca.x + oc0.y*ca.y + oc0.z*ca.z + oc0.w*ca.w
                + oc1.x*cb.x + oc1.y*cb.y + oc1.z*cb.z + oc1.w*cb.w;
#pragma unroll
      for(int off=1; off<8; off<<=1) acc += __shfl_xor(acc, off);
      if(q == 0) aput(&lgp[((size_t)b_att*Vn + v)*8 + ts], acc);
    }
    gbar2(wsu, ++gg);
  }
}

// ============================================================================
// bf16-input fallback: round-1 structure (passed), per-batch barrier groups.
// ============================================================================
__device__ __forceinline__ void gbar8(unsigned int* bar){
  asm volatile("s_waitcnt vmcnt(0)" ::: "memory");
  __syncthreads();
  if(threadIdx.x==0){
    unsigned int g = uget(bar+1);
    unsigned int p = __hip_atomic_fetch_add(bar, 1u, __ATOMIC_RELAXED, __HIP_MEMORY_SCOPE_AGENT);
    if(p == g*NTS + (NTS-1)){
      __hip_atomic_store(bar+1, g+1u, __ATOMIC_RELAXED, __HIP_MEMORY_SCOPE_AGENT);
    } else {
      while(uget(bar+1) == g) __builtin_amdgcn_s_sleep(2);
    }
  }
  __syncthreads();
  asm volatile("" ::: "memory");
}

__global__ __launch_bounds__(NTHREADS, 2)
void speller_bf16(const unsigned short* __restrict__ lf, const unsigned short* __restrict__ wih,
                  const unsigned short* __restrict__ whh, const unsigned short* __restrict__ bih,
                  const unsigned short* __restrict__ bhh, const unsigned short* __restrict__ wout,
                  const unsigned short* __restrict__ bout, unsigned short* __restrict__ out,
                  float* __restrict__ ws)
{
  { unsigned int fl = __hip_atomic_load((unsigned int*)ws + 512, __ATOMIC_ACQUIRE, __HIP_MEMORY_SCOPE_AGENT);
    if(fl != 1u) return; }
  const int tid = threadIdx.x;
  const int b   = (int)(blockIdx.x >> 3);
  const int ts  = (int)(blockIdx.x & 7);

  extern __shared__ char smem[];
  unsigned short* lf_s = (unsigned short*)smem;           // [128][512] bf16
  float* h_s   = (float*)(smem + 131072);
  float* ctx_s = h_s + 512;
  float* e_s   = ctx_s + 512;
  float* p_s   = e_s + 128;
  float* lg_s  = p_s + 128;
  float* red_s = lg_s + 64;
  float* c_s   = red_s + 32;
  int*   i_s   = (int*)(c_s + 64);

  unsigned int* bar = (unsigned int*)ws + (size_t)b*16 + 4;
  float* hbuf = ws + 1024  + (size_t)b*Hn;
  float* mstB = ws + WS_MST + (size_t)b*NTS;
  float* lstB = ws + WS_LST + (size_t)b*NTS;
  float* ctxpB= ws + WS_CTXP + (size_t)b*NTS*Dn;

  {
    const uint4* s4 = (const uint4*)(lf + ((size_t)b*Tn + (size_t)ts*TT) * Dn);
    uint4* d4 = (uint4*)lf_s;
#pragma unroll
    for(int i=0;i<16;i++) d4[tid + i*NTHREADS] = s4[tid + i*NTHREADS];
  }
  h_s[tid] = 0.f;
  if(tid < 64) c_s[tid] = 0.f;
  if(tid == 0) i_s[0] = 0;
  __syncthreads();

  for(int s = 0; s <= Sn; ++s){
    if(s > 0){
      if(tid < NTS){ red_s[16+tid] = aget(&mstB[tid]); red_s[24+tid] = aget(&lstB[tid]); }
      __syncthreads();
      if(tid == 0){
        float m = -3.0e38f;
#pragma unroll
        for(int j=0;j<NTS;j++) m = fmaxf(m, red_s[16+j]);
        float l = 0.f;
#pragma unroll
        for(int j=0;j<NTS;j++){ float fac = expf(red_s[16+j]-m); red_s[j]=fac; l += fac*red_s[24+j]; }
        red_s[8]=m; red_s[9]=l;
      }
      __syncthreads();
      const float gm = red_s[8];
      const float gl = red_s[9];
      {
        float acc = 0.f;
#pragma unroll
        for(int j=0;j<NTS;j++) acc += red_s[j] * aget(&ctxpB[(size_t)j*Dn + tid]);
        ctx_s[tid] = acc / gl;
      }
      if(tid < TT)
        out[OUT_ATT + ((size_t)(s-1)*Bn + b)*Tn + (size_t)ts*TT + tid] = f2bf(expf(e_s[tid]-gm)/gl);
      __syncthreads();
      {
        const int j = tid >> 3, ks = tid & 7;
        const unsigned short* wr = wout + (size_t)j*(2*Hn) + ks*128;
        float acc;
        if(ks < 4) acc = dot64g(wr, h_s + ks*128)       + dot64g(wr+64, h_s + ks*128 + 64);
        else       acc = dot64g(wr, ctx_s + (ks-4)*128) + dot64g(wr+64, ctx_s + (ks-4)*128 + 64);
#pragma unroll
        for(int off=1; off<8; off<<=1) acc += __shfl_xor(acc, off);
        if(ks==0) lg_s[j] = acc + bfu(bout[j]);
      }
      __syncthreads();
      if(tid < Vn){
        const float lv = lg_s[tid];
        float mv = lv; int mi = tid;
#pragma unroll
        for(int off=1; off<64; off<<=1){
          float ov = __shfl_xor(mv, off);
          int   oi = __shfl_xor(mi, off);
          if(ov > mv || (ov == mv && oi < mi)){ mv = ov; mi = oi; }
        }
        float se = expf(lv - mv);
#pragma unroll
        for(int off=1; off<64; off<<=1) se += __shfl_xor(se, off);
        if(ts == 0) out[((size_t)(s-1)*Bn + b)*Vn + tid] = f2bf(lv - mv - logf(se));
        if(tid == 0) i_s[0] = mi;
      }
      __syncthreads();
    } else {
      ctx_s[tid] = bfu(lf[(size_t)b*Tn*Dn + tid]);
      __syncthreads();
    }

    if(s == Sn) break;

    {
      const int u  = tid >> 3;
      const int ks = tid & 7;
      const int uu = ts*64 + u;
      const unsigned short* wi0 = wih + (size_t)(       uu)*KIH + 64 + ks*64;
      const unsigned short* wi1 = wih + (size_t)(  Hn + uu)*KIH + 64 + ks*64;
      const unsigned short* wi2 = wih + (size_t)(2*Hn + uu)*KIH + 64 + ks*64;
      const unsigned short* wi3 = wih + (size_t)(3*Hn + uu)*KIH + 64 + ks*64;
      const unsigned short* wh0 = whh + (size_t)(       uu)*Hn + ks*64;
      const unsigned short* wh1 = whh + (size_t)(  Hn + uu)*Hn + ks*64;
      const unsigned short* wh2 = whh + (size_t)(2*Hn + uu)*Hn + ks*64;
      const unsigned short* wh3 = whh + (size_t)(3*Hn + uu)*Hn + ks*64;
      const float4* xc = (const float4*)(ctx_s + ks*64);
      const float4* xh4 = (const float4*)(h_s   + ks*64);
      float a0=0.f,a1=0.f,a2=0.f,a3=0.f;
#pragma unroll
      for(int i=0;i<8;i++){
        float4 p0 = xc[2*i], p1 = xc[2*i+1];
        a0 += dot8(ld8(wi0+8*i), p0, p1);
        a1 += dot8(ld8(wi1+8*i), p0, p1);
        a2 += dot8(ld8(wi2+8*i), p0, p1);
        a3 += dot8(ld8(wi3+8*i), p0, p1);
      }
#pragma unroll
      for(int i=0;i<8;i++){
        float4 p0 = xh4[2*i], p1 = xh4[2*i+1];
        a0 += dot8(ld8(wh0+8*i), p0, p1);
        a1 += dot8(ld8(wh1+8*i), p0, p1);
        a2 += dot8(ld8(wh2+8*i), p0, p1);
        a3 += dot8(ld8(wh3+8*i), p0, p1);
      }
#pragma unroll
      for(int off=1; off<8; off<<=1){
        a0 += __shfl_xor(a0, off);
        a1 += __shfl_xor(a1, off);
        a2 += __shfl_xor(a2, off);
        a3 += __shfl_xor(a3, off);
      }
      if(ks == 0){
        const int pidx = i_s[0];
        const int r0 = uu, r1 = Hn+uu, r2 = 2*Hn+uu, r3 = 3*Hn+uu;
        float gi = a0 + bfu(wih[(size_t)r0*KIH + pidx]) + bfu(bih[r0]) + bfu(bhh[r0]);
        float gf = a1 + bfu(wih[(size_t)r1*KIH + pidx]) + bfu(bih[r1]) + bfu(bhh[r1]);
        float gg = a2 + bfu(wih[(size_t)r2*KIH + pidx]) + bfu(bih[r2]) + bfu(bhh[r2]);
        float go = a3 + bfu(wih[(size_t)r3*KIH + pidx]) + bfu(bih[r3]) + bfu(bhh[r3]);
        gi = sigm(gi); gf = sigm(gf); gg = tnh(gg); go = sigm(go);
        float c = gf*c_s[u] + gi*gg;
        c_s[u] = c;
        aput(&hbuf[uu], go * tnh(c));
      }
    }
    gbar8(bar);

    h_s[tid] = aget(&hbuf[tid]);
    __syncthreads();
    {
      const int t2 = tid >> 3;
      const int q  = tid & 7;
      const float4* hq = (const float4*)(h_s + q*64);
      float ea=0.f, eb=0.f;
      const unsigned short* la = lf_s + (size_t)(2*t2  )*Dn + q*64;
      const unsigned short* lb = lf_s + (size_t)(2*t2+1)*Dn + q*64;
#pragma unroll
      for(int i=0;i<8;i++){
        float4 p0 = hq[2*i], p1 = hq[2*i+1];
        ea += dot8(ld8(la+8*i), p0, p1);
        eb += dot8(ld8(lb+8*i), p0, p1);
      }
#pragma unroll
      for(int off=1; off<8; off<<=1){ ea += __shfl_xor(ea,off); eb += __shfl_xor(eb,off); }
      if(q==0){ e_s[2*t2] = ea; e_s[2*t2+1] = eb; }
    }
    __syncthreads();
    if(tid < 64){
      float v = fmaxf(e_s[tid], e_s[tid+64]);
#pragma unroll
      for(int off=1; off<64; off<<=1) v = fmaxf(v, __shfl_xor(v,off));
      if(tid==0) red_s[10] = v;
    }
    __syncthreads();
    if(tid < TT) p_s[tid] = expf(e_s[tid] - red_s[10]);
    __syncthreads();
    if(tid < 64){
      float v = p_s[tid] + p_s[tid+64];
#pragma unroll
      for(int off=1; off<64; off<<=1) v += __shfl_xor(v,off);
      if(tid==0){ aput(&mstB[ts], red_s[10]); aput(&lstB[ts], v); }
    }
    {
      float acc = 0.f;
      const unsigned short* col = lf_s + tid;
#pragma unroll 4
      for(int t=0;t<TT;t++) acc += p_s[t] * bfu(col[(size_t)t*Dn]);
      aput(&ctxpB[(size_t)ts*Dn + tid], acc);
    }
    gbar8(bar);
  }
}

extern "C" void kernel_launch(void* const* d_in, const int* in_sizes, int n_in,
                              void* d_out, int out_size, void* d_ws, size_t ws_size,
                              hipStream_t stream) {
  (void)in_sizes; (void)n_in; (void)out_size; (void)ws_size;
  float* ws = (float*)d_ws;

  hipFuncSetAttribute(reinterpret_cast<const void*>(&speller_v3),
                      hipFuncAttributeMaxDynamicSharedMemorySize, LDS_BYTES);
  hipFuncSetAttribute(reinterpret_cast<const void*>(&speller_bf16),
                      hipFuncAttributeMaxDynamicSharedMemorySize, LDS_BYTES);
  // barriers + flags live in the first 4 KB (d_ws is poisoned before every launch)
  hipMemsetAsync(d_ws, 0, 4096, stream);
  dtype_probe<<<dim3(1), dim3(64), 0, stream>>>((const unsigned short*)d_in[3],
                                                (unsigned int*)d_ws + 512);
  speller_v3<<<dim3(NBLK), dim3(NTHREADS), LDS_BYTES, stream>>>(
      (const float*)d_in[0], (const float*)d_in[1], (const float*)d_in[2],
      (const float*)d_in[3], (const float*)d_in[4], (const float*)d_in[5],
      (const float*)d_in[6], (float*)d_out, ws);
  speller_bf16<<<dim3(NBLK), dim3(NTHREADS), LDS_BYTES, stream>>>(
      (const unsigned short*)d_in[0], (const unsigned short*)d_in[1],
      (const unsigned short*)d_in[2], (const unsigned short*)d_in[3],
      (const unsigned short*)d_in[4], (const unsigned short*)d_in[5],
      (const unsigned short*)d_in[6], (unsigned short*)d_out, ws);
}